// Round 4
// baseline (1757.294 us; speedup 1.0000x reference)
//
#include <hip/hip_runtime.h>

// N=64, D=128, EMB=64, OUTG=64, A=512, B=256, G=8
// group_mask[i,j] = (j//2 == i).
//
// k_f v2: block = (b, n1): Mt=512 rows (all 8 g of one b), Nt1=128 layer1 cols.
//   aggr A-frags in registers; emb folded into fp32 base_f; B staged to LDS
//   via global_load_lds (dbuf); h0 packed u32 in swizzled LDS; layer2 partial
//   dots -> ws, reduced by k_out. fp16-split x3 MFMA throughout.

typedef _Float16 half8 __attribute__((ext_vector_type(8)));
typedef float    f32x4 __attribute__((ext_vector_type(4)));
typedef uint32_t u32x4 __attribute__((ext_vector_type(4)));

#define MFMA16(a, b, c) __builtin_amdgcn_mfma_f32_16x16x32_f16(a, b, c, 0, 0, 0)

__device__ __forceinline__ float leaky(float v) { return v >= 0.f ? v : 0.01f * v; }

__device__ __forceinline__ uint32_t packsplit(float v) {
    _Float16 hi = (_Float16)v;
    _Float16 lo = (_Float16)(v - (float)hi);
    union { _Float16 f; unsigned short u; } a, c;
    a.f = hi; c.f = lo;
    return (uint32_t)a.u | ((uint32_t)c.u << 16);
}

__device__ __forceinline__ void unpackA(u32x4 w0, u32x4 w1, half8& Ah, half8& Al) {
    union { u32x4 u; half8 h; } ah, al;
    ah.u[0] = (w0[0] & 0xffffu) | (w0[1] << 16);
    ah.u[1] = (w0[2] & 0xffffu) | (w0[3] << 16);
    ah.u[2] = (w1[0] & 0xffffu) | (w1[1] << 16);
    ah.u[3] = (w1[2] & 0xffffu) | (w1[3] << 16);
    al.u[0] = (w0[0] >> 16) | (w0[1] & 0xffff0000u);
    al.u[1] = (w0[2] >> 16) | (w0[3] & 0xffff0000u);
    al.u[2] = (w1[0] >> 16) | (w1[1] & 0xffff0000u);
    al.u[3] = (w1[2] >> 16) | (w1[3] & 0xffff0000u);
    Ah = ah.h; Al = al.h;
}

__device__ __forceinline__ void gl_lds16(const void* g, void* l) {
    __builtin_amdgcn_global_load_lds(
        (const __attribute__((address_space(1))) unsigned int*)g,
        (__attribute__((address_space(3))) unsigned int*)l, 16, 0, 0);
}

// ---------------- prep kernels ----------------

__global__ void k_base(const float* __restrict__ emb,
                       const float* __restrict__ gw0, const float* __restrict__ gb0,
                       const float* __restrict__ fw0, const float* __restrict__ fb0,
                       float* __restrict__ base_g, float* __restrict__ base_f)
{
    int blk = blockIdx.x;            // 256 blocks
    int n     = blk >> 2;
    int half  = (blk >> 1) & 1;
    int which = blk & 1;
    int c = half * 256 + threadIdx.x;
    const float* W    = which ? fw0 : gw0;
    const float* bias = which ? fb0 : gb0;
    float* dst        = which ? base_f : base_g;
    int off           = which ? 64 : 128;
    const float* e = emb + n * 64;
    float acc = bias[c];
    #pragma unroll 8
    for (int k = 0; k < 64; ++k)
        acc = fmaf(e[k], W[(off + k) * 512 + c], acc);
    dst[n * 512 + c] = acc;
}

// w2P[node][a][d] = fw2[a][2*node+d]  (float2-friendly for the layer2 epilogue)
__global__ void k_w2p(const float* __restrict__ fw2, float* __restrict__ w2P)
{
    int tid = blockIdx.x * 256 + threadIdx.x;   // grid 256 -> 65536
    int c = tid >> 9, a = tid & 511;            // c = 2*node+d
    int node = c >> 1, d = c & 1;
    w2P[(node * 512 + a) * 2 + d] = fw2[a * 128 + c];
}

// Split fw1 (512x512) and fw0 rows 0..63 (aggr part) into f16 hi/lo
// B-fragment-linear layouts.
//   fw1:  frag[(kstep*32 + ntg)*64 + l][j] = fw1[kstep*32+(l>>4)*8+j][ntg*16+(l&15)]
//   fw0:  frag[(ntg*2 + ks)*64 + l][j]     = fw0[ks*32+(l>>4)*8+j][ntg*16+(l&15)]
__global__ void k_splitw(const float* __restrict__ fw0, const float* __restrict__ fw1,
                         _Float16* __restrict__ fw0h, _Float16* __restrict__ fw0l,
                         _Float16* __restrict__ fw1h, _Float16* __restrict__ fw1l)
{
    int tid = blockIdx.x * 256 + threadIdx.x;
    if (blockIdx.x < 128) {                       // fw1: 16 ksteps x 32 ntg
        int l = tid & 63, grp = tid >> 6;
        int kstep = grp >> 5, ntg = grp & 31;
        #pragma unroll
        for (int j = 0; j < 8; ++j) {
            int k = kstep * 32 + (l >> 4) * 8 + j;
            int n = ntg * 16 + (l & 15);
            float v = fw1[k * 512 + n];
            _Float16 h = (_Float16)v;
            fw1h[tid * 8 + j] = h;
            fw1l[tid * 8 + j] = (_Float16)(v - (float)h);
        }
    } else {                                      // fw0 rows 0..63: fr = ntg*2+ks
        int t2 = tid - 32768;                     // 0..4095
        int l = t2 & 63, fr = t2 >> 6;            // fr 0..63
        int ntg = fr >> 1, ks = fr & 1;
        #pragma unroll
        for (int j = 0; j < 8; ++j) {
            int k = ks * 32 + (l >> 4) * 8 + j;
            int n = ntg * 16 + (l & 15);
            float v = fw0[k * 512 + n];
            _Float16 h = (_Float16)v;
            fw0h[t2 * 8 + j] = h;
            fw0l[t2 * 8 + j] = (_Float16)(v - (float)h);
        }
    }
}

// ---------------- g-MLP (unchanged, verified) ----------------

template <int KLEN, int LDSSTRIDE>
__device__ __forceinline__ void gemm16x2(const float* __restrict__ W,
                                         const float* sh, int c0, int c1,
                                         float (&acc0)[16], float (&acc1)[16])
{
    for (int k = 0; k < KLEN; k += 4) {
        float wa0 = W[(k + 0) * 512 + c0], wb0 = W[(k + 0) * 512 + c1];
        float wa1 = W[(k + 1) * 512 + c0], wb1 = W[(k + 1) * 512 + c1];
        float wa2 = W[(k + 2) * 512 + c0], wb2 = W[(k + 2) * 512 + c1];
        float wa3 = W[(k + 3) * 512 + c0], wb3 = W[(k + 3) * 512 + c1];
        #pragma unroll
        for (int i = 0; i < 16; ++i) {
            float4 h = *reinterpret_cast<const float4*>(&sh[i * LDSSTRIDE + k]);
            acc0[i] = fmaf(h.x, wa0, acc0[i]); acc1[i] = fmaf(h.x, wb0, acc1[i]);
            acc0[i] = fmaf(h.y, wa1, acc0[i]); acc1[i] = fmaf(h.y, wb1, acc1[i]);
            acc0[i] = fmaf(h.z, wa2, acc0[i]); acc1[i] = fmaf(h.z, wb2, acc1[i]);
            acc0[i] = fmaf(h.w, wa3, acc0[i]); acc1[i] = fmaf(h.w, wb3, acc1[i]);
        }
    }
}

__global__ __launch_bounds__(256, 4) void k_embs(
    const float* __restrict__ samples, const float* __restrict__ gw0,
    const float* __restrict__ gw1, const float* __restrict__ gb1,
    const float* __restrict__ gw2, const float* __restrict__ gb2,
    const float* __restrict__ base_g, float* __restrict__ emb_s)
{
    __shared__ __align__(16) float sh[16 * 512];
    const int t  = threadIdx.x;
    const int r0 = blockIdx.x * 16;
    const int b  = r0 >> 6;
    const int c0 = t, c1 = t + 256;

    #pragma unroll
    for (int i = 0; i < 16; ++i) {
        int n = (r0 + i) & 63;
        float s0 = samples[b * 128 + 2 * n];
        float s1 = samples[b * 128 + 2 * n + 1];
        const float* w0a = gw0 + (2 * n) * 512;
        const float* w0b = gw0 + (2 * n + 1) * 512;
        const float* bg  = base_g + n * 512;
        float v0 = fmaf(s0, w0a[c0], fmaf(s1, w0b[c0], bg[c0]));
        float v1 = fmaf(s0, w0a[c1], fmaf(s1, w0b[c1], bg[c1]));
        sh[i * 512 + c0] = leaky(v0);
        sh[i * 512 + c1] = leaky(v1);
    }
    __syncthreads();

    float acc0[16], acc1[16];
    {
        float bb0 = gb1[c0], bb1 = gb1[c1];
        #pragma unroll
        for (int i = 0; i < 16; ++i) { acc0[i] = bb0; acc1[i] = bb1; }
    }
    gemm16x2<512, 512>(gw1, sh, c0, c1, acc0, acc1);
    __syncthreads();
    #pragma unroll
    for (int i = 0; i < 16; ++i) {
        sh[i * 512 + c0] = leaky(acc0[i]);
        sh[i * 512 + c1] = leaky(acc1[i]);
    }
    __syncthreads();

    int i  = t >> 4;
    int kb = (t & 15) * 4;
    float4 o = *reinterpret_cast<const float4*>(&gb2[kb]);
    for (int a = 0; a < 512; ++a) {
        float  h  = sh[i * 512 + a];
        float4 wv = *reinterpret_cast<const float4*>(&gw2[a * 64 + kb]);
        o.x = fmaf(h, wv.x, o.x); o.y = fmaf(h, wv.y, o.y);
        o.z = fmaf(h, wv.z, o.z); o.w = fmaf(h, wv.w, o.w);
    }
    *reinterpret_cast<float4*>(&emb_s[(r0 + i) * 64 + kb]) = o;
}

// ---------------- fused f-MLP v2 ----------------
// LDS (112 KB):
//   [0, 65536)        h0chunk packed u32 [512 rows][8 slots x 16B], slot-XOR swizzled
//                     (prologue: emb_s fp32 16 KB at offset 0)
//   [65536, 81920)    B0 dbuf: 2 x 8 KB  (8 frags of 1 KB: slot = pl*4 + nt2*2 + ks)
//   [81920, 114688)   B1 dbuf: 2 x 16 KB (pl*8KB + nt*1KB)

#define H0_BASE 0
#define B0_BASE 65536
#define B1_BASE 81920

__global__ __launch_bounds__(512, 2) void k_f(
    const float* __restrict__ graphs, const float* __restrict__ w,
    const float* __restrict__ emb_s, const float* __restrict__ base_f,
    const float* __restrict__ fb1, const float* __restrict__ w2P,
    const _Float16* __restrict__ fw0h, const _Float16* __restrict__ fw0l,
    const _Float16* __restrict__ fw1h, const _Float16* __restrict__ fw1l,
    float* __restrict__ part)
{
    __shared__ __align__(16) unsigned char smem[114688];
    const int t  = threadIdx.x;
    const int l  = t & 63;
    const int wv = t >> 6;        // wave = g
    const int q  = l >> 4;        // lane quad
    const int lr = l & 15;

    int bid = blockIdx.x;                        // 1024
    int wg  = (bid & 7) * 128 + (bid >> 3);      // XCD swizzle: 2 XCDs per n1
    const int n1 = wg >> 8;                      // 0..3
    const int b  = wg & 255;

    // ---- prologue: async stage emb_s[b] (16 KB), B-step0 ----
    {
        const float* eb = emb_s + b * 4096;
        gl_lds16(eb + wv * 256 + l * 4,        smem + H0_BASE + wv * 1024);
        gl_lds16(eb + 2048 + wv * 256 + l * 4, smem + H0_BASE + 8192 + wv * 1024);
        gl_lds16(fw1h + ((0 * 32 + n1 * 8 + wv) * 64 + l) * 8, smem + B1_BASE + wv * 1024);
        gl_lds16(fw1l + ((0 * 32 + n1 * 8 + wv) * 64 + l) * 8, smem + B1_BASE + 8192 + wv * 1024);
        const _Float16* f0p = (wv < 4) ? fw0h : fw0l;
        gl_lds16(f0p + ((4 * 0 + (wv & 3)) * 64 + l) * 8, smem + B0_BASE + wv * 1024);
    }
    __syncthreads();

    // ---- aggr[g=wv][rows][k0..63] into register A-fragments ----
    float ag[4][2][8];
    #pragma unroll
    for (int mt = 0; mt < 4; ++mt)
        #pragma unroll
        for (int ks = 0; ks < 2; ++ks)
            #pragma unroll
            for (int jj = 0; jj < 8; ++jj) ag[mt][ks][jj] = 0.f;

    {
        const float* gw = graphs + wv * 4096;
        const float* el = (const float*)(smem + H0_BASE);
        for (int j = 0; j < 64; ++j) {
            const float* er = el + j * 64 + q * 8;
            float4 e00 = *(const float4*)(er);
            float4 e01 = *(const float4*)(er + 4);
            float4 e10 = *(const float4*)(er + 32);
            float4 e11 = *(const float4*)(er + 36);
            #pragma unroll
            for (int mt = 0; mt < 4; ++mt) {
                float wa = gw[j * 64 + mt * 16 + lr] * w[j * 64 + mt * 16 + lr];
                ag[mt][0][0] = fmaf(wa, e00.x, ag[mt][0][0]);
                ag[mt][0][1] = fmaf(wa, e00.y, ag[mt][0][1]);
                ag[mt][0][2] = fmaf(wa, e00.z, ag[mt][0][2]);
                ag[mt][0][3] = fmaf(wa, e00.w, ag[mt][0][3]);
                ag[mt][0][4] = fmaf(wa, e01.x, ag[mt][0][4]);
                ag[mt][0][5] = fmaf(wa, e01.y, ag[mt][0][5]);
                ag[mt][0][6] = fmaf(wa, e01.z, ag[mt][0][6]);
                ag[mt][0][7] = fmaf(wa, e01.w, ag[mt][0][7]);
                ag[mt][1][0] = fmaf(wa, e10.x, ag[mt][1][0]);
                ag[mt][1][1] = fmaf(wa, e10.y, ag[mt][1][1]);
                ag[mt][1][2] = fmaf(wa, e10.z, ag[mt][1][2]);
                ag[mt][1][3] = fmaf(wa, e10.w, ag[mt][1][3]);
                ag[mt][1][4] = fmaf(wa, e11.x, ag[mt][1][4]);
                ag[mt][1][5] = fmaf(wa, e11.y, ag[mt][1][5]);
                ag[mt][1][6] = fmaf(wa, e11.z, ag[mt][1][6]);
                ag[mt][1][7] = fmaf(wa, e11.w, ag[mt][1][7]);
            }
        }
    }
    // convert aggr -> f16 hi/lo fragments (64 VGPR)
    half8 agh[4][2], agl[4][2];
    #pragma unroll
    for (int mt = 0; mt < 4; ++mt)
        #pragma unroll
        for (int ks = 0; ks < 2; ++ks)
            #pragma unroll
            for (int jj = 0; jj < 8; ++jj) {
                float v = ag[mt][ks][jj];
                _Float16 h = (_Float16)v;
                agh[mt][ks][jj] = h;
                agl[mt][ks][jj] = (_Float16)(v - (float)h);
            }

    f32x4 zero4 = {0.f, 0.f, 0.f, 0.f};
    f32x4 acc1[4][8];
    #pragma unroll
    for (int mt = 0; mt < 4; ++mt)
        #pragma unroll
        for (int nt = 0; nt < 8; ++nt) acc1[mt][nt] = zero4;

    // ---- main loop: 16 K-steps of 32 h0-cols ----
    for (int kk = 0; kk < 16; ++kk) {
        const int pb = kk & 1;
        __syncthreads();   // stage[kk] arrived (vmcnt drained); h0[kk-1] consumed

        // issue stage kk+1 early (hides under layer0)
        if (kk < 15) {
            const int pn = pb ^ 1;
            gl_lds16(fw1h + (((kk + 1) * 32 + n1 * 8 + wv) * 64 + l) * 8,
                     smem + B1_BASE + pn * 16384 + wv * 1024);
            gl_lds16(fw1l + (((kk + 1) * 32 + n1 * 8 + wv) * 64 + l) * 8,
                     smem + B1_BASE + pn * 16384 + 8192 + wv * 1024);
            const _Float16* f0p = (wv < 4) ? fw0h : fw0l;
            gl_lds16(f0p + ((4 * (kk + 1) + (wv & 3)) * 64 + l) * 8,
                     smem + B0_BASE + pn * 8192 + wv * 1024);
        }

        // ---- layer0: h0 cols [kk*32, +32), K=64 from aggr regs ----
        #pragma unroll
        for (int nt2 = 0; nt2 < 2; ++nt2) {
            f32x4 c0[4] = {zero4, zero4, zero4, zero4};
            #pragma unroll
            for (int ks = 0; ks < 2; ++ks) {
                half8 Bh = *(const half8*)(smem + B0_BASE + pb * 8192 + ((0 * 4 + nt2 * 2 + ks) << 10) + l * 16);
                half8 Bl = *(const half8*)(smem + B0_BASE + pb * 8192 + ((1 * 4 + nt2 * 2 + ks) << 10) + l * 16);
                #pragma unroll
                for (int mt = 0; mt < 4; ++mt) {
                    c0[mt] = MFMA16(agh[mt][ks], Bh, c0[mt]);
                    c0[mt] = MFMA16(agh[mt][ks], Bl, c0[mt]);
                    c0[mt] = MFMA16(agl[mt][ks], Bh, c0[mt]);
                }
            }
            // epilogue: + base_f (holds fb0 + emb part, exact fp32), leaky, pack
            #pragma unroll
            for (int mt = 0; mt < 4; ++mt) {
                #pragma unroll
                for (int r = 0; r < 4; ++r) {
                    int node = mt * 16 + q * 4 + r;
                    int row  = wv * 64 + node;
                    int kcol = nt2 * 16 + lr;
                    float v  = c0[mt][r] + base_f[node * 512 + kk * 32 + kcol];
                    v = leaky(v);
                    *(uint32_t*)(smem + H0_BASE + row * 128 +
                                 (((kcol >> 2) ^ (row & 7)) << 4) + (kcol & 3) * 4) = packsplit(v);
                }
            }
        }
        __syncthreads();   // h0 visible

        // ---- layer1: K-chunk kk (32 cols of h0) ----
        half8 A1h[4], A1l[4];
        #pragma unroll
        for (int mt = 0; mt < 4; ++mt) {
            int row = wv * 64 + mt * 16 + lr;
            int f = row & 7;
            const unsigned char* rb = smem + H0_BASE + row * 128;
            u32x4 w0 = *(const u32x4*)(rb + (((2 * q) ^ f) << 4));
            u32x4 w1 = *(const u32x4*)(rb + (((2 * q + 1) ^ f) << 4));
            unpackA(w0, w1, A1h[mt], A1l[mt]);
        }
        #pragma unroll
        for (int nt = 0; nt < 8; ++nt) {
            half8 Bh = *(const half8*)(smem + B1_BASE + pb * 16384 + nt * 1024 + l * 16);
            half8 Bl = *(const half8*)(smem + B1_BASE + pb * 16384 + 8192 + nt * 1024 + l * 16);
            #pragma unroll
            for (int mt = 0; mt < 4; ++mt) {
                acc1[mt][nt] = MFMA16(A1h[mt], Bh, acc1[mt][nt]);
                acc1[mt][nt] = MFMA16(A1h[mt], Bl, acc1[mt][nt]);
                acc1[mt][nt] = MFMA16(A1l[mt], Bh, acc1[mt][nt]);
            }
        }
    }

    // ---- h1 = leaky(acc1 + fb1); layer2 partial dot; write partials ----
    #pragma unroll
    for (int nt = 0; nt < 8; ++nt) {
        float bb = fb1[n1 * 128 + nt * 16 + lr];
        #pragma unroll
        for (int mt = 0; mt < 4; ++mt)
            #pragma unroll
            for (int r = 0; r < 4; ++r)
                acc1[mt][nt][r] = leaky(acc1[mt][nt][r] + bb);
    }
    #pragma unroll
    for (int mt = 0; mt < 4; ++mt) {
        #pragma unroll
        for (int r = 0; r < 4; ++r) {
            int node = mt * 16 + q * 4 + r;
            float s0 = 0.f, s1 = 0.f;
            #pragma unroll
            for (int nt = 0; nt < 8; ++nt) {
                float2 w2 = *(const float2*)(w2P + ((node * 512 + n1 * 128 + nt * 16 + lr) << 1));
                s0 = fmaf(acc1[mt][nt][r], w2.x, s0);
                s1 = fmaf(acc1[mt][nt][r], w2.y, s1);
            }
            s0 += __shfl_xor(s0, 1, 64); s0 += __shfl_xor(s0, 2, 64);
            s0 += __shfl_xor(s0, 4, 64); s0 += __shfl_xor(s0, 8, 64);
            s1 += __shfl_xor(s1, 1, 64); s1 += __shfl_xor(s1, 2, 64);
            s1 += __shfl_xor(s1, 4, 64); s1 += __shfl_xor(s1, 8, 64);
            if (lr == 0) {
                float* pp = part + n1 * 262144 + (b * 8 + wv) * 128 + 2 * node;
                pp[0] = s0;
                pp[1] = s1;
            }
        }
    }
}

__global__ void k_out(const float* __restrict__ part, const float* __restrict__ fb2,
                      float* __restrict__ out)
{
    int i = blockIdx.x * 256 + threadIdx.x;   // 262144
    float s = part[i] + part[262144 + i] + part[524288 + i] + part[786432 + i];
    out[i] = s + fb2[i & 127];
}

// ---------------- launch ----------------

extern "C" void kernel_launch(void* const* d_in, const int* in_sizes, int n_in,
                              void* d_out, int out_size, void* d_ws, size_t ws_size,
                              hipStream_t stream)
{
    const float* samples    = (const float*)d_in[0];
    const float* graphs     = (const float*)d_in[1];
    const float* embeddings = (const float*)d_in[3];
    const float* w          = (const float*)d_in[4];
    const float* g_w0 = (const float*)d_in[5];
    const float* g_b0 = (const float*)d_in[6];
    const float* g_w1 = (const float*)d_in[7];
    const float* g_b1 = (const float*)d_in[8];
    const float* g_w2 = (const float*)d_in[9];
    const float* g_b2 = (const float*)d_in[10];
    const float* f_w0 = (const float*)d_in[11];
    const float* f_b0 = (const float*)d_in[12];
    const float* f_w1 = (const float*)d_in[13];
    const float* f_b1 = (const float*)d_in[14];
    const float* f_w2 = (const float*)d_in[15];
    const float* f_b2 = (const float*)d_in[16];
    float* out = (float*)d_out;

    float* ws     = (float*)d_ws;
    float* base_g = ws;                    // 32768
    float* base_f = ws + 32768;            // 32768
    float* w2P    = ws + 65536;            // 65536
    float* emb_s  = ws + 131072;           // 1048576
    float* part   = ws + 1179648;          // 1048576 (4 x 262144)
    _Float16* f16base = (_Float16*)(ws + 2228224);
    _Float16* fw1h = f16base;              // 262144
    _Float16* fw1l = f16base + 262144;     // 262144
    _Float16* fw0h = f16base + 524288;     // 32768
    _Float16* fw0l = f16base + 557056;     // 32768   (ws total ~10.1 MB)

    hipLaunchKernelGGL(k_base, dim3(256), dim3(256), 0, stream,
                       embeddings, g_w0, g_b0, f_w0, f_b0, base_g, base_f);
    hipLaunchKernelGGL(k_w2p, dim3(256), dim3(256), 0, stream, f_w2, w2P);
    hipLaunchKernelGGL(k_splitw, dim3(144), dim3(256), 0, stream,
                       f_w0, f_w1, fw0h, fw0l, fw1h, fw1l);
    hipLaunchKernelGGL(k_embs, dim3(1024), dim3(256), 0, stream,
                       samples, g_w0, g_w1, g_b1, g_w2, g_b2, base_g, emb_s);
    hipLaunchKernelGGL(k_f, dim3(1024), dim3(512), 0, stream,
                       graphs, w, emb_s, base_f, f_b1, w2P,
                       fw0h, fw0l, fw1h, fw1l, part);
    hipLaunchKernelGGL(k_out, dim3(1024), dim3(256), 0, stream,
                       part, f_b2, out);
}

// Round 5
// 619.560 us; speedup vs baseline: 2.8364x; 2.8364x over previous
//
#include <hip/hip_runtime.h>
#include <stdint.h>

// N=64, D=128, EMB=64, OUTG=64, A=512, B=256, G=8
// group_mask[i,j] = (j//2 == i).
//
// De-fused f-MLP:
//   k_h0: per (b,g): aggr (fp32) -> split-f16 MFMA layer0 (K=64) + base_f
//         -> leaky -> packed u32 [f16hi|f16lo] h0, PRE-SWIZZLED, NT-stored to ws.
//   k_l1: per (b,g): layer1 GEMM 64x512x512 (A from h0 via global_load_lds dbuf,
//         one barrier/K-step; B = fw1 frags from L2) + fused bias/leaky/layer2.
// fp16-split x3 MFMA: a = a_hi+a_lo; a*b ~= AhBh + AhBl + AlBh (fp32 acc).

typedef _Float16 half8 __attribute__((ext_vector_type(8)));
typedef float    f32x4 __attribute__((ext_vector_type(4)));
typedef uint32_t u32x4 __attribute__((ext_vector_type(4)));

#define MFMA16(a, b, c) __builtin_amdgcn_mfma_f32_16x16x32_f16(a, b, c, 0, 0, 0)

__device__ __forceinline__ float leaky(float v) { return v >= 0.f ? v : 0.01f * v; }

__device__ __forceinline__ uint32_t packsplit(float v) {
    _Float16 hi = (_Float16)v;
    _Float16 lo = (_Float16)(v - (float)hi);
    union { _Float16 f; unsigned short u; } a, c;
    a.f = hi; c.f = lo;
    return (uint32_t)a.u | ((uint32_t)c.u << 16);
}

__device__ __forceinline__ void unpackA(u32x4 w0, u32x4 w1, half8& Ah, half8& Al) {
    union { u32x4 u; half8 h; } ah, al;
    ah.u[0] = (w0[0] & 0xffffu) | (w0[1] << 16);
    ah.u[1] = (w0[2] & 0xffffu) | (w0[3] << 16);
    ah.u[2] = (w1[0] & 0xffffu) | (w1[1] << 16);
    ah.u[3] = (w1[2] & 0xffffu) | (w1[3] << 16);
    al.u[0] = (w0[0] >> 16) | (w0[1] & 0xffff0000u);
    al.u[1] = (w0[2] >> 16) | (w0[3] & 0xffff0000u);
    al.u[2] = (w1[0] >> 16) | (w1[1] & 0xffff0000u);
    al.u[3] = (w1[2] >> 16) | (w1[3] & 0xffff0000u);
    Ah = ah.h; Al = al.h;
}

__device__ __forceinline__ void gl_lds16(const void* g, void* l) {
    __builtin_amdgcn_global_load_lds(
        (const __attribute__((address_space(1))) unsigned int*)g,
        (__attribute__((address_space(3))) unsigned int*)l, 16, 0, 0);
}

// ---------------- prep kernels ----------------

__global__ void k_base(const float* __restrict__ emb,
                       const float* __restrict__ gw0, const float* __restrict__ gb0,
                       const float* __restrict__ fw0, const float* __restrict__ fb0,
                       float* __restrict__ base_g, float* __restrict__ base_f)
{
    int blk = blockIdx.x;            // 256 blocks
    int n     = blk >> 2;
    int half  = (blk >> 1) & 1;
    int which = blk & 1;
    int c = half * 256 + threadIdx.x;
    const float* W    = which ? fw0 : gw0;
    const float* bias = which ? fb0 : gb0;
    float* dst        = which ? base_f : base_g;
    int off           = which ? 64 : 128;
    const float* e = emb + n * 64;
    float acc = bias[c];
    #pragma unroll 8
    for (int k = 0; k < 64; ++k)
        acc = fmaf(e[k], W[(off + k) * 512 + c], acc);
    dst[n * 512 + c] = acc;
}

// w2P[node][a][d] = fw2[a][2*node+d]
__global__ void k_w2p(const float* __restrict__ fw2, float* __restrict__ w2P)
{
    int tid = blockIdx.x * 256 + threadIdx.x;   // grid 256 -> 65536
    int c = tid >> 9, a = tid & 511;            // c = 2*node+d
    int node = c >> 1, d = c & 1;
    w2P[(node * 512 + a) * 2 + d] = fw2[a * 128 + c];
}

// Split fw1 (512x512) and fw0 rows 0..63 into f16 hi/lo B-fragment-linear:
//   frag[(kstep*32 + ntg)*64 + l][j] = W[kstep*32 + (l>>4)*8 + j][ntg*16 + (l&15)]
__global__ void k_splitw(const float* __restrict__ fw0, const float* __restrict__ fw1,
                         _Float16* __restrict__ fw0h, _Float16* __restrict__ fw0l,
                         _Float16* __restrict__ fw1h, _Float16* __restrict__ fw1l)
{
    int tid = blockIdx.x * 256 + threadIdx.x;
    if (blockIdx.x < 128) {                       // fw1: 16 ksteps x 32 ntg
        int l = tid & 63, grp = tid >> 6;
        int kstep = grp >> 5, ntg = grp & 31;
        #pragma unroll
        for (int j = 0; j < 8; ++j) {
            int k = kstep * 32 + (l >> 4) * 8 + j;
            int n = ntg * 16 + (l & 15);
            float v = fw1[k * 512 + n];
            _Float16 h = (_Float16)v;
            fw1h[tid * 8 + j] = h;
            fw1l[tid * 8 + j] = (_Float16)(v - (float)h);
        }
    } else {                                      // fw0 rows 0..63: 2 ksteps x 32 ntg
        int t2 = tid - 32768;                     // 0..4095
        int l = t2 & 63, grp = t2 >> 6;
        int kstep = grp >> 5, ntg = grp & 31;
        #pragma unroll
        for (int j = 0; j < 8; ++j) {
            int k = kstep * 32 + (l >> 4) * 8 + j;
            int n = ntg * 16 + (l & 15);
            float v = fw0[k * 512 + n];
            _Float16 h = (_Float16)v;
            fw0h[t2 * 8 + j] = h;
            fw0l[t2 * 8 + j] = (_Float16)(v - (float)h);
        }
    }
}

// ---------------- g-MLP (unchanged, verified) ----------------

template <int KLEN, int LDSSTRIDE>
__device__ __forceinline__ void gemm16x2(const float* __restrict__ W,
                                         const float* sh, int c0, int c1,
                                         float (&acc0)[16], float (&acc1)[16])
{
    for (int k = 0; k < KLEN; k += 4) {
        float wa0 = W[(k + 0) * 512 + c0], wb0 = W[(k + 0) * 512 + c1];
        float wa1 = W[(k + 1) * 512 + c0], wb1 = W[(k + 1) * 512 + c1];
        float wa2 = W[(k + 2) * 512 + c0], wb2 = W[(k + 2) * 512 + c1];
        float wa3 = W[(k + 3) * 512 + c0], wb3 = W[(k + 3) * 512 + c1];
        #pragma unroll
        for (int i = 0; i < 16; ++i) {
            float4 h = *reinterpret_cast<const float4*>(&sh[i * LDSSTRIDE + k]);
            acc0[i] = fmaf(h.x, wa0, acc0[i]); acc1[i] = fmaf(h.x, wb0, acc1[i]);
            acc0[i] = fmaf(h.y, wa1, acc0[i]); acc1[i] = fmaf(h.y, wb1, acc1[i]);
            acc0[i] = fmaf(h.z, wa2, acc0[i]); acc1[i] = fmaf(h.z, wb2, acc1[i]);
            acc0[i] = fmaf(h.w, wa3, acc0[i]); acc1[i] = fmaf(h.w, wb3, acc1[i]);
        }
    }
}

__global__ __launch_bounds__(256, 4) void k_embs(
    const float* __restrict__ samples, const float* __restrict__ gw0,
    const float* __restrict__ gw1, const float* __restrict__ gb1,
    const float* __restrict__ gw2, const float* __restrict__ gb2,
    const float* __restrict__ base_g, float* __restrict__ emb_s)
{
    __shared__ __align__(16) float sh[16 * 512];
    const int t  = threadIdx.x;
    const int r0 = blockIdx.x * 16;
    const int b  = r0 >> 6;
    const int c0 = t, c1 = t + 256;

    #pragma unroll
    for (int i = 0; i < 16; ++i) {
        int n = (r0 + i) & 63;
        float s0 = samples[b * 128 + 2 * n];
        float s1 = samples[b * 128 + 2 * n + 1];
        const float* w0a = gw0 + (2 * n) * 512;
        const float* w0b = gw0 + (2 * n + 1) * 512;
        const float* bg  = base_g + n * 512;
        float v0 = fmaf(s0, w0a[c0], fmaf(s1, w0b[c0], bg[c0]));
        float v1 = fmaf(s0, w0a[c1], fmaf(s1, w0b[c1], bg[c1]));
        sh[i * 512 + c0] = leaky(v0);
        sh[i * 512 + c1] = leaky(v1);
    }
    __syncthreads();

    float acc0[16], acc1[16];
    {
        float bb0 = gb1[c0], bb1 = gb1[c1];
        #pragma unroll
        for (int i = 0; i < 16; ++i) { acc0[i] = bb0; acc1[i] = bb1; }
    }
    gemm16x2<512, 512>(gw1, sh, c0, c1, acc0, acc1);
    __syncthreads();
    #pragma unroll
    for (int i = 0; i < 16; ++i) {
        sh[i * 512 + c0] = leaky(acc0[i]);
        sh[i * 512 + c1] = leaky(acc1[i]);
    }
    __syncthreads();

    int i  = t >> 4;
    int kb = (t & 15) * 4;
    float4 o = *reinterpret_cast<const float4*>(&gb2[kb]);
    for (int a = 0; a < 512; ++a) {
        float  h  = sh[i * 512 + a];
        float4 wv = *reinterpret_cast<const float4*>(&gw2[a * 64 + kb]);
        o.x = fmaf(h, wv.x, o.x); o.y = fmaf(h, wv.y, o.y);
        o.z = fmaf(h, wv.z, o.z); o.w = fmaf(h, wv.w, o.w);
    }
    *reinterpret_cast<float4*>(&emb_s[(r0 + i) * 64 + kb]) = o;
}

// ---------------- k_h0: aggr + layer0 -> packed h0 ----------------
// h0pk layout (u32): [m_blk][kstep 16][row 64][32], u32-index within row line:
//   ((klocal>>2) ^ (row&7))*4 + (klocal&3)   (pre-swizzled for k_l1's ds_reads)

__global__ __launch_bounds__(512, 4) void k_h0(
    const float* __restrict__ graphs, const float* __restrict__ w,
    const float* __restrict__ emb_s, const float* __restrict__ base_f,
    const _Float16* __restrict__ fw0h, const _Float16* __restrict__ fw0l,
    uint32_t* __restrict__ h0pk, int mblk_base)
{
    __shared__ __align__(16) unsigned char smem[49152];
    float* s_emb  = (float*)smem;            // 16 KB
    float* s_wadj = (float*)(smem + 16384);  // 16 KB; A0 packed at +32768 (16 KB)
    const int t = threadIdx.x, l = t & 63, wv = t >> 6;
    const int q = l >> 4, lr = l & 15;
    const int m_blk = mblk_base + blockIdx.x;
    const int b = m_blk >> 3, g = m_blk & 7;

    {   // stage emb_s[b] and wadj = graphs[g]*w
        const float* eb = emb_s + b * 4096;
        const float* gb = graphs + g * 4096;
        int idx = t * 8;
        *(float4*)(s_emb + idx)     = *(const float4*)(eb + idx);
        *(float4*)(s_emb + idx + 4) = *(const float4*)(eb + idx + 4);
        float4 g0 = *(const float4*)(gb + idx);
        float4 w0 = *(const float4*)(w + idx);
        float4 m0; m0.x = g0.x*w0.x; m0.y = g0.y*w0.y; m0.z = g0.z*w0.z; m0.w = g0.w*w0.w;
        *(float4*)(s_wadj + idx) = m0;
        float4 g1 = *(const float4*)(gb + idx + 4);
        float4 w1 = *(const float4*)(w + idx + 4);
        float4 m1; m1.x = g1.x*w1.x; m1.y = g1.y*w1.y; m1.z = g1.z*w1.z; m1.w = g1.w*w1.w;
        *(float4*)(s_wadj + idx + 4) = m1;
    }
    __syncthreads();

    {   // aggr[m][k]: thread m = t>>3, k0 = (t&7)*8; split-pack to A0
        int m = t >> 3, k0 = (t & 7) * 8;
        float acc[8] = {0.f,0.f,0.f,0.f,0.f,0.f,0.f,0.f};
        for (int j = 0; j < 64; ++j) {
            float wc = s_wadj[j * 64 + m];
            float4 e0 = *(const float4*)(s_emb + j * 64 + k0);
            float4 e1 = *(const float4*)(s_emb + j * 64 + k0 + 4);
            acc[0] = fmaf(wc, e0.x, acc[0]); acc[1] = fmaf(wc, e0.y, acc[1]);
            acc[2] = fmaf(wc, e0.z, acc[2]); acc[3] = fmaf(wc, e0.w, acc[3]);
            acc[4] = fmaf(wc, e1.x, acc[4]); acc[5] = fmaf(wc, e1.y, acc[5]);
            acc[6] = fmaf(wc, e1.z, acc[6]); acc[7] = fmaf(wc, e1.w, acc[7]);
        }
        int f = m & 7;
        u32x4 p0, p1;
        #pragma unroll
        for (int e = 0; e < 4; ++e) { p0[e] = packsplit(acc[e]); p1[e] = packsplit(acc[4 + e]); }
        int g0i = k0 >> 2;   // even
        *(u32x4*)(smem + 32768 + m * 256 + ((g0i ^ f) << 4))       = p0;
        *(u32x4*)(smem + 32768 + m * 256 + (((g0i + 1) ^ f) << 4)) = p1;
    }
    __syncthreads();

    // layer0 MFMA: wave wv owns ntg = wv*4..+4 (64 cols)
    f32x4 zero4 = {0.f, 0.f, 0.f, 0.f};
    f32x4 c0[4][4];
    #pragma unroll
    for (int mt = 0; mt < 4; ++mt)
        #pragma unroll
        for (int nn = 0; nn < 4; ++nn) c0[mt][nn] = zero4;

    #pragma unroll
    for (int ks = 0; ks < 2; ++ks) {
        half8 Ah[4], Al[4];
        #pragma unroll
        for (int mt = 0; mt < 4; ++mt) {
            int m = mt * 16 + lr, f = m & 7;
            const unsigned char* rb = smem + 32768 + m * 256;
            int gb2 = ks * 8 + 2 * q;
            u32x4 w0 = *(const u32x4*)(rb + (((gb2)     ^ f) << 4));
            u32x4 w1 = *(const u32x4*)(rb + (((gb2 + 1) ^ f) << 4));
            unpackA(w0, w1, Ah[mt], Al[mt]);
        }
        #pragma unroll
        for (int nn = 0; nn < 4; ++nn) {
            int ntg = wv * 4 + nn;
            long boff = (long)((ks * 32 + ntg) * 64 + l) * 8;
            half8 Bh = *(const half8*)(fw0h + boff);
            half8 Bl = *(const half8*)(fw0l + boff);
            #pragma unroll
            for (int mt = 0; mt < 4; ++mt) {
                c0[mt][nn] = MFMA16(Ah[mt], Bh, c0[mt][nn]);
                c0[mt][nn] = MFMA16(Ah[mt], Bl, c0[mt][nn]);
                c0[mt][nn] = MFMA16(Al[mt], Bh, c0[mt][nn]);
            }
        }
    }

    // epilogue: +base_f, leaky, packsplit, NT store (pre-swizzled layout)
    uint32_t* h0b = h0pk + (size_t)m_blk * 32768;
    #pragma unroll
    for (int mt = 0; mt < 4; ++mt) {
        #pragma unroll
        for (int nn = 0; nn < 4; ++nn) {
            int ntg = wv * 4 + nn;
            int kstep = ntg >> 1;
            int klo = (ntg & 1) * 16 + lr;
            #pragma unroll
            for (int r = 0; r < 4; ++r) {
                int node = mt * 16 + q * 4 + r;
                float v = leaky(c0[mt][nn][r] + base_f[node * 512 + ntg * 16 + lr]);
                int sw = (((klo >> 2) ^ (node & 7)) << 2) + (klo & 3);
                __builtin_nontemporal_store(packsplit(v),
                    h0b + kstep * 2048 + node * 32 + sw);
            }
        }
    }
}

// ---------------- k_l1: layer1 GEMM + fused layer2 ----------------
// LDS: [0,16384) A dbuf (2 x 8 KB); [16384,18432) part[4][64][2] f32

__global__ __launch_bounds__(512, 4) void k_l1(
    const uint32_t* __restrict__ h0pk,
    const _Float16* __restrict__ fw1h, const _Float16* __restrict__ fw1l,
    const float* __restrict__ fb1, const float* __restrict__ w2P,
    const float* __restrict__ fb2, float* __restrict__ out, int mblk_base)
{
    __shared__ __align__(16) unsigned char smem[18432];
    const int t = threadIdx.x, l = t & 63, wv = t >> 6;
    const int wm = wv >> 2, wn = wv & 3, q = l >> 4, lr = l & 15;
    const int m_blk = mblk_base + blockIdx.x;
    const uint32_t* h0b = h0pk + (size_t)m_blk * 32768;

    gl_lds16(h0b + t * 4, smem + t * 16);   // stage kk=0 -> buf0

    f32x4 zero4 = {0.f, 0.f, 0.f, 0.f};
    f32x4 acc[2][8];
    #pragma unroll
    for (int mt = 0; mt < 2; ++mt)
        #pragma unroll
        for (int nt = 0; nt < 8; ++nt) acc[mt][nt] = zero4;

    for (int kk = 0; kk < 16; ++kk) {
        const int pb = kk & 1;
        __syncthreads();                       // A[kk] in buf[pb]; buf[pb^1] free
        if (kk < 15)
            gl_lds16(h0b + (kk + 1) * 2048 + t * 4,
                     smem + (pb ^ 1) * 8192 + t * 16);

        half8 Ah[2], Al[2];
        #pragma unroll
        for (int mt = 0; mt < 2; ++mt) {
            int row = wm * 32 + mt * 16 + lr, f = row & 7;
            const unsigned char* rb = smem + pb * 8192 + row * 128;
            u32x4 w0 = *(const u32x4*)(rb + (((2 * q)     ^ f) << 4));
            u32x4 w1 = *(const u32x4*)(rb + (((2 * q + 1) ^ f) << 4));
            unpackA(w0, w1, Ah[mt], Al[mt]);
        }
        #pragma unroll
        for (int nt = 0; nt < 8; ++nt) {
            long boff = (long)((kk * 32 + wn * 8 + nt) * 64 + l) * 8;
            half8 Bh = *(const half8*)(fw1h + boff);
            half8 Bl = *(const half8*)(fw1l + boff);
            #pragma unroll
            for (int mt = 0; mt < 2; ++mt) {
                acc[mt][nt] = MFMA16(Ah[mt], Bh, acc[mt][nt]);
                acc[mt][nt] = MFMA16(Ah[mt], Bl, acc[mt][nt]);
                acc[mt][nt] = MFMA16(Al[mt], Bh, acc[mt][nt]);
            }
        }
    }

    // h1 = leaky(acc+fb1); layer2 partial dot per node; reduce over lr then wn
    float* part = (float*)(smem + 16384);
    #pragma unroll
    for (int mt = 0; mt < 2; ++mt) {
        float s0[4] = {0.f,0.f,0.f,0.f}, s1[4] = {0.f,0.f,0.f,0.f};
        #pragma unroll
        for (int nt = 0; nt < 8; ++nt) {
            int col = wn * 128 + nt * 16 + lr;
            float bb = fb1[col];
            #pragma unroll
            for (int r = 0; r < 4; ++r) {
                int node = wm * 32 + mt * 16 + q * 4 + r;
                float h1 = leaky(acc[mt][nt][r] + bb);
                float2 w2 = *(const float2*)(w2P + (((size_t)node * 512 + col) << 1));
                s0[r] = fmaf(h1, w2.x, s0[r]);
                s1[r] = fmaf(h1, w2.y, s1[r]);
            }
        }
        #pragma unroll
        for (int r = 0; r < 4; ++r) {
            s0[r] += __shfl_xor(s0[r], 1, 64); s0[r] += __shfl_xor(s0[r], 2, 64);
            s0[r] += __shfl_xor(s0[r], 4, 64); s0[r] += __shfl_xor(s0[r], 8, 64);
            s1[r] += __shfl_xor(s1[r], 1, 64); s1[r] += __shfl_xor(s1[r], 2, 64);
            s1[r] += __shfl_xor(s1[r], 4, 64); s1[r] += __shfl_xor(s1[r], 8, 64);
            if (lr == 0) {
                int node = wm * 32 + mt * 16 + q * 4 + r;
                part[(wn * 64 + node) * 2 + 0] = s0[r];
                part[(wn * 64 + node) * 2 + 1] = s1[r];
            }
        }
    }
    __syncthreads();
    if (t < 128) {
        int node = t >> 1, d = t & 1;
        float s = part[(0 * 64 + node) * 2 + d] + part[(1 * 64 + node) * 2 + d]
                + part[(2 * 64 + node) * 2 + d] + part[(3 * 64 + node) * 2 + d];
        out[m_blk * 128 + node * 2 + d] = s + fb2[node * 2 + d];
    }
}

// ---------------- launch ----------------

extern "C" void kernel_launch(void* const* d_in, const int* in_sizes, int n_in,
                              void* d_out, int out_size, void* d_ws, size_t ws_size,
                              hipStream_t stream)
{
    const float* samples    = (const float*)d_in[0];
    const float* graphs     = (const float*)d_in[1];
    const float* embeddings = (const float*)d_in[3];
    const float* w          = (const float*)d_in[4];
    const float* g_w0 = (const float*)d_in[5];
    const float* g_b0 = (const float*)d_in[6];
    const float* g_w1 = (const float*)d_in[7];
    const float* g_b1 = (const float*)d_in[8];
    const float* g_w2 = (const float*)d_in[9];
    const float* g_b2 = (const float*)d_in[10];
    const float* f_w0 = (const float*)d_in[11];
    const float* f_b0 = (const float*)d_in[12];
    const float* f_w1 = (const float*)d_in[13];
    const float* f_b1 = (const float*)d_in[14];
    const float* f_w2 = (const float*)d_in[15];
    const float* f_b2 = (const float*)d_in[16];
    float* out = (float*)d_out;

    float* ws     = (float*)d_ws;
    float* base_g = ws;                    // 32768
    float* base_f = ws + 32768;            // 32768
    float* w2P    = ws + 65536;            // 65536
    float* emb_s  = ws + 131072;           // 1048576
    _Float16* fw1h = (_Float16*)(ws + 1179648);   // 262144 halfs
    _Float16* fw1l = (_Float16*)(ws + 1310720);   // 262144 halfs
    _Float16* fw0h = (_Float16*)(ws + 1441792);   // 32768 halfs
    _Float16* fw0l = (_Float16*)(ws + 1458176);   // 32768 halfs
    uint32_t* h0pk = (uint32_t*)(ws + 1474560);   // up to 64M u32 (256 MB)

    // chunk the h0 buffer to whatever ws provides
    size_t ws_u32 = ws_size / 4;
    size_t avail  = (ws_u32 > 1474560) ? ws_u32 - 1474560 : 0;
    int chunk = (int)(avail / 32768);           // m-blocks per pass (64 rows each)
    if (chunk > 2048) chunk = 2048;
    if (chunk < 1) chunk = 1;                   // (ws assumed >= ~6.2 MB)
    int nrounds = (2048 + chunk - 1) / chunk;

    hipLaunchKernelGGL(k_base, dim3(256), dim3(256), 0, stream,
                       embeddings, g_w0, g_b0, f_w0, f_b0, base_g, base_f);
    hipLaunchKernelGGL(k_w2p, dim3(256), dim3(256), 0, stream, f_w2, w2P);
    hipLaunchKernelGGL(k_splitw, dim3(144), dim3(256), 0, stream,
                       f_w0, f_w1, fw0h, fw0l, fw1h, fw1l);
    hipLaunchKernelGGL(k_embs, dim3(1024), dim3(256), 0, stream,
                       samples, g_w0, g_w1, g_b1, g_w2, g_b2, base_g, emb_s);

    for (int r = 0; r < nrounds; ++r) {
        int base = r * chunk;
        int n = (2048 - base < chunk) ? (2048 - base) : chunk;
        hipLaunchKernelGGL(k_h0, dim3(n), dim3(512), 0, stream,
                           graphs, w, emb_s, base_f, fw0h, fw0l, h0pk - (size_t)base * 32768, base);
        hipLaunchKernelGGL(k_l1, dim3(n), dim3(512), 0, stream,
                           h0pk - (size_t)base * 32768, fw1h, fw1l, f_b1, w2P, f_b2, out, base);
    }
}

// Round 6
// 509.297 us; speedup vs baseline: 3.4504x; 1.2165x over previous
//
#include <hip/hip_runtime.h>
#include <stdint.h>

// N=64, D=128, EMB=64, OUTG=64, A=512, B=256, G=8
// group_mask[i,j] = (j//2 == i).
//
// Pipeline (all heavy GEMMs on split-f16 MFMA: a=a_hi+a_lo,
// a*b ~= AhBh + AhBl + AlBh, fp32 acc):
//   k_gmlp: g-MLP per batch b: h0g chunks (VALU) -> LDS -> layer1 MFMA
//           (gw1 frags) -> h1 two-half LDS -> layer2 MFMA (gw2 frags) -> emb_s
//   k_h0:   per (b,g): aggr fp32 -> layer0 MFMA (fw0 frags) + base_f -> leaky
//           -> packed u32 [f16hi|f16lo], pre-swizzled, CACHEABLE store (L3-resident)
//   k_l1:   per m-blk PAIR (M=128): layer1 GEMM (A via global_load_lds dbuf,
//           B = fw1 frags from L2) + fused bias/leaky/layer2 epilogue.

typedef _Float16 half8 __attribute__((ext_vector_type(8)));
typedef float    f32x4 __attribute__((ext_vector_type(4)));
typedef uint32_t u32x4 __attribute__((ext_vector_type(4)));

#define MFMA16(a, b, c) __builtin_amdgcn_mfma_f32_16x16x32_f16(a, b, c, 0, 0, 0)

__device__ __forceinline__ float leaky(float v) { return v >= 0.f ? v : 0.01f * v; }

__device__ __forceinline__ uint32_t packsplit(float v) {
    _Float16 hi = (_Float16)v;
    _Float16 lo = (_Float16)(v - (float)hi);
    union { _Float16 f; unsigned short u; } a, c;
    a.f = hi; c.f = lo;
    return (uint32_t)a.u | ((uint32_t)c.u << 16);
}

__device__ __forceinline__ void unpackA(u32x4 w0, u32x4 w1, half8& Ah, half8& Al) {
    union { u32x4 u; half8 h; } ah, al;
    ah.u[0] = (w0[0] & 0xffffu) | (w0[1] << 16);
    ah.u[1] = (w0[2] & 0xffffu) | (w0[3] << 16);
    ah.u[2] = (w1[0] & 0xffffu) | (w1[1] << 16);
    ah.u[3] = (w1[2] & 0xffffu) | (w1[3] << 16);
    al.u[0] = (w0[0] >> 16) | (w0[1] & 0xffff0000u);
    al.u[1] = (w0[2] >> 16) | (w0[3] & 0xffff0000u);
    al.u[2] = (w1[0] >> 16) | (w1[1] & 0xffff0000u);
    al.u[3] = (w1[2] >> 16) | (w1[3] & 0xffff0000u);
    Ah = ah.h; Al = al.h;
}

__device__ __forceinline__ void gl_lds16(const void* g, void* l) {
    __builtin_amdgcn_global_load_lds(
        (const __attribute__((address_space(1))) unsigned int*)g,
        (__attribute__((address_space(3))) unsigned int*)l, 16, 0, 0);
}

// ---------------- prep kernels ----------------

__global__ void k_base(const float* __restrict__ emb,
                       const float* __restrict__ gw0, const float* __restrict__ gb0,
                       const float* __restrict__ fw0, const float* __restrict__ fb0,
                       float* __restrict__ base_g, float* __restrict__ base_f)
{
    int blk = blockIdx.x;            // 256 blocks
    int n     = blk >> 2;
    int half  = (blk >> 1) & 1;
    int which = blk & 1;
    int c = half * 256 + threadIdx.x;
    const float* W    = which ? fw0 : gw0;
    const float* bias = which ? fb0 : gb0;
    float* dst        = which ? base_f : base_g;
    int off           = which ? 64 : 128;
    const float* e = emb + n * 64;
    float acc = bias[c];
    #pragma unroll 8
    for (int k = 0; k < 64; ++k)
        acc = fmaf(e[k], W[(off + k) * 512 + c], acc);
    dst[n * 512 + c] = acc;
}

// w2P[node][a][d] = fw2[a][2*node+d]
__global__ void k_w2p(const float* __restrict__ fw2, float* __restrict__ w2P)
{
    int tid = blockIdx.x * 256 + threadIdx.x;   // grid 256 -> 65536
    int c = tid >> 9, a = tid & 511;            // c = 2*node+d
    int node = c >> 1, d = c & 1;
    w2P[(node * 512 + a) * 2 + d] = fw2[a * 128 + c];
}

// Fragment-linear f16 hi/lo splits:
//  fw1/gw1 (512x512): frag[(kstep*32+ntg)*64+l][j] = W[kstep*32+(l>>4)*8+j][ntg*16+(l&15)]
//  fw0 rows 0..63:    frag[(kstep*32+ntg)*64+l][j] (kstep 0..1)
//  gw2 (512x64):      frag[(kstep*4+ntg)*64+l][j]  = gw2[kstep*32+(l>>4)*8+j][ntg*16+(l&15)]
__global__ void k_splitw(const float* __restrict__ fw0, const float* __restrict__ fw1,
                         const float* __restrict__ gw1, const float* __restrict__ gw2,
                         _Float16* __restrict__ fw0h, _Float16* __restrict__ fw0l,
                         _Float16* __restrict__ fw1h, _Float16* __restrict__ fw1l,
                         _Float16* __restrict__ gw1h, _Float16* __restrict__ gw1l,
                         _Float16* __restrict__ gw2h, _Float16* __restrict__ gw2l)
{
    int tid = blockIdx.x * 256 + threadIdx.x;
    if (blockIdx.x < 128) {                       // fw1
        int l = tid & 63, grp = tid >> 6;
        int kstep = grp >> 5, ntg = grp & 31;
        #pragma unroll
        for (int j = 0; j < 8; ++j) {
            int k = kstep * 32 + (l >> 4) * 8 + j;
            int n = ntg * 16 + (l & 15);
            float v = fw1[k * 512 + n];
            _Float16 h = (_Float16)v;
            fw1h[tid * 8 + j] = h;
            fw1l[tid * 8 + j] = (_Float16)(v - (float)h);
        }
    } else if (blockIdx.x < 144) {                // fw0 rows 0..63
        int t2 = tid - 32768;
        int l = t2 & 63, grp = t2 >> 6;
        int kstep = grp >> 5, ntg = grp & 31;
        #pragma unroll
        for (int j = 0; j < 8; ++j) {
            int k = kstep * 32 + (l >> 4) * 8 + j;
            int n = ntg * 16 + (l & 15);
            float v = fw0[k * 512 + n];
            _Float16 h = (_Float16)v;
            fw0h[t2 * 8 + j] = h;
            fw0l[t2 * 8 + j] = (_Float16)(v - (float)h);
        }
    } else if (blockIdx.x < 272) {                // gw1
        int t4 = tid - 36864;
        int l = t4 & 63, grp = t4 >> 6;
        int kstep = grp >> 5, ntg = grp & 31;
        #pragma unroll
        for (int j = 0; j < 8; ++j) {
            int k = kstep * 32 + (l >> 4) * 8 + j;
            int n = ntg * 16 + (l & 15);
            float v = gw1[k * 512 + n];
            _Float16 h = (_Float16)v;
            gw1h[t4 * 8 + j] = h;
            gw1l[t4 * 8 + j] = (_Float16)(v - (float)h);
        }
    } else {                                      // gw2
        int t3 = tid - 69632;                     // 0..4095
        int l = t3 & 63, grp = t3 >> 6;           // grp 0..63
        int kstep = grp >> 2, ntg = grp & 3;
        #pragma unroll
        for (int j = 0; j < 8; ++j) {
            int k = kstep * 32 + (l >> 4) * 8 + j;
            int n = ntg * 16 + (l & 15);
            float v = gw2[k * 64 + n];
            _Float16 h = (_Float16)v;
            gw2h[t3 * 8 + j] = h;
            gw2l[t3 * 8 + j] = (_Float16)(v - (float)h);
        }
    }
}

// ---------------- k_gmlp: g-MLP on MFMA ----------------
// One block per batch b (256 blocks, 512 thr, 8 waves).
// LDS (80 KB): [0,16K) h0g stage dbuf (2 x 8 KB); [16K,80K) h1 packed (8 ksteps x 8 KB)

__global__ __launch_bounds__(512, 2) void k_gmlp(
    const float* __restrict__ samples, const float* __restrict__ gw0,
    const float* __restrict__ base_g, const float* __restrict__ gb1,
    const float* __restrict__ gb2,
    const _Float16* __restrict__ gw1h, const _Float16* __restrict__ gw1l,
    const _Float16* __restrict__ gw2h, const _Float16* __restrict__ gw2l,
    float* __restrict__ emb_s)
{
    __shared__ __align__(16) unsigned char smem[81920];
    const int t = threadIdx.x, l = t & 63, wv = t >> 6;
    const int q = l >> 4, lr = l & 15;
    const int b = blockIdx.x;

    f32x4 zero4 = {0.f, 0.f, 0.f, 0.f};
    f32x4 acc[4][4];
    #pragma unroll
    for (int mt = 0; mt < 4; ++mt)
        #pragma unroll
        for (int nt = 0; nt < 4; ++nt) acc[mt][nt] = zero4;

    // stage h0g chunk kk (32 cols) into buffer bq
    auto stage = [&](int kk, int bq) {
        #pragma unroll
        for (int it = 0; it < 4; ++it) {
            int n = it * 16 + (t >> 5);
            int c = kk * 32 + (t & 31);
            float s0 = samples[b * 128 + 2 * n];
            float s1 = samples[b * 128 + 2 * n + 1];
            float v = fmaf(s0, gw0[(2 * n) * 512 + c],
                      fmaf(s1, gw0[(2 * n + 1) * 512 + c], base_g[n * 512 + c]));
            v = leaky(v);
            int kl = t & 31;
            int sw = (((kl >> 2) ^ (n & 7)) << 2) | (kl & 3);
            *(uint32_t*)(smem + bq * 8192 + n * 128 + sw * 4) = packsplit(v);
        }
    };

    stage(0, 0);
    for (int kk = 0; kk < 16; ++kk) {
        const int pb = kk & 1;
        __syncthreads();                 // stage kk visible
        if (kk < 15) stage(kk + 1, pb ^ 1);

        half8 Ah[4], Al[4];
        #pragma unroll
        for (int mt = 0; mt < 4; ++mt) {
            int row = mt * 16 + lr, f = row & 7;
            const unsigned char* rb = smem + pb * 8192 + row * 128;
            u32x4 w0 = *(const u32x4*)(rb + (((2 * q) ^ f) << 4));
            u32x4 w1 = *(const u32x4*)(rb + (((2 * q + 1) ^ f) << 4));
            unpackA(w0, w1, Ah[mt], Al[mt]);
        }
        #pragma unroll
        for (int nt = 0; nt < 4; ++nt) {
            int ntg = wv * 4 + nt;
            long boff = (long)((kk * 32 + ntg) * 64 + l) * 8;
            half8 Bh = *(const half8*)(gw1h + boff);
            half8 Bl = *(const half8*)(gw1l + boff);
            #pragma unroll
            for (int mt = 0; mt < 4; ++mt) {
                acc[mt][nt] = MFMA16(Ah[mt], Bh, acc[mt][nt]);
                acc[mt][nt] = MFMA16(Ah[mt], Bl, acc[mt][nt]);
                acc[mt][nt] = MFMA16(Al[mt], Bh, acc[mt][nt]);
            }
        }
    }

    // ---- layer2 via two-half h1 materialization ----
    const int mt2 = wv >> 1;
    f32x4 acc2[2] = {zero4, zero4};
    #pragma unroll
    for (int half = 0; half < 2; ++half) {
        __syncthreads();                 // prior reads of h1 area done
        if ((wv >> 2) == half) {
            #pragma unroll
            for (int nt = 0; nt < 4; ++nt) {
                int col = wv * 64 + nt * 16 + lr;
                float bb = gb1[col];
                int ksl = (col >> 5) - half * 8;
                int kl = col & 31;
                #pragma unroll
                for (int mt = 0; mt < 4; ++mt)
                    #pragma unroll
                    for (int r = 0; r < 4; ++r) {
                        int row = mt * 16 + q * 4 + r;
                        float v = leaky(acc[mt][nt][r] + bb);
                        int sw = (((kl >> 2) ^ (row & 7)) << 2) | (kl & 3);
                        *(uint32_t*)(smem + 16384 + ksl * 8192 + row * 128 + sw * 4)
                            = packsplit(v);
                    }
            }
        }
        __syncthreads();
        #pragma unroll
        for (int ks = 0; ks < 8; ++ks) {
            int kstep = half * 8 + ks;
            int row = mt2 * 16 + lr, f = row & 7;
            const unsigned char* rb = smem + 16384 + ks * 8192 + row * 128;
            u32x4 w0 = *(const u32x4*)(rb + (((2 * q) ^ f) << 4));
            u32x4 w1 = *(const u32x4*)(rb + (((2 * q + 1) ^ f) << 4));
            half8 Ah2, Al2;
            unpackA(w0, w1, Ah2, Al2);
            #pragma unroll
            for (int nt = 0; nt < 2; ++nt) {
                int ntg = (wv & 1) * 2 + nt;
                long boff = (long)((kstep * 4 + ntg) * 64 + l) * 8;
                half8 Bh = *(const half8*)(gw2h + boff);
                half8 Bl = *(const half8*)(gw2l + boff);
                acc2[nt] = MFMA16(Ah2, Bh, acc2[nt]);
                acc2[nt] = MFMA16(Ah2, Bl, acc2[nt]);
                acc2[nt] = MFMA16(Al2, Bh, acc2[nt]);
            }
        }
    }
    #pragma unroll
    for (int nt = 0; nt < 2; ++nt) {
        int col = ((wv & 1) * 2 + nt) * 16 + lr;
        float bb = gb2[col];
        #pragma unroll
        for (int r = 0; r < 4; ++r) {
            int node = mt2 * 16 + q * 4 + r;
            emb_s[b * 4096 + node * 64 + col] = acc2[nt][r] + bb;
        }
    }
}

// ---------------- k_h0: aggr + layer0 -> packed h0 (L3-resident) ----------------
// h0pk (u32): [m_blk][kstep 16][row 64][32], pre-swizzled:
//   u32 idx in row line = ((klocal>>2) ^ (row&7))*4 + (klocal&3)

__global__ __launch_bounds__(512, 4) void k_h0(
    const float* __restrict__ graphs, const float* __restrict__ w,
    const float* __restrict__ emb_s, const float* __restrict__ base_f,
    const _Float16* __restrict__ fw0h, const _Float16* __restrict__ fw0l,
    uint32_t* __restrict__ h0pk, int mblk_base)
{
    __shared__ __align__(16) unsigned char smem[49152];
    float* s_emb  = (float*)smem;            // 16 KB
    float* s_wadj = (float*)(smem + 16384);  // 16 KB; A0 packed at +32768
    const int t = threadIdx.x, l = t & 63, wv = t >> 6;
    const int q = l >> 4, lr = l & 15;
    const int m_blk = mblk_base + blockIdx.x;
    const int b = m_blk >> 3, g = m_blk & 7;

    {
        const float* eb = emb_s + b * 4096;
        const float* gb = graphs + g * 4096;
        int idx = t * 8;
        *(float4*)(s_emb + idx)     = *(const float4*)(eb + idx);
        *(float4*)(s_emb + idx + 4) = *(const float4*)(eb + idx + 4);
        float4 g0 = *(const float4*)(gb + idx);
        float4 w0 = *(const float4*)(w + idx);
        float4 m0; m0.x = g0.x*w0.x; m0.y = g0.y*w0.y; m0.z = g0.z*w0.z; m0.w = g0.w*w0.w;
        *(float4*)(s_wadj + idx) = m0;
        float4 g1 = *(const float4*)(gb + idx + 4);
        float4 w1 = *(const float4*)(w + idx + 4);
        float4 m1; m1.x = g1.x*w1.x; m1.y = g1.y*w1.y; m1.z = g1.z*w1.z; m1.w = g1.w*w1.w;
        *(float4*)(s_wadj + idx + 4) = m1;
    }
    __syncthreads();

    {
        int m = t >> 3, k0 = (t & 7) * 8;
        float acc[8] = {0.f,0.f,0.f,0.f,0.f,0.f,0.f,0.f};
        for (int j = 0; j < 64; ++j) {
            float wc = s_wadj[j * 64 + m];
            float4 e0 = *(const float4*)(s_emb + j * 64 + k0);
            float4 e1 = *(const float4*)(s_emb + j * 64 + k0 + 4);
            acc[0] = fmaf(wc, e0.x, acc[0]); acc[1] = fmaf(wc, e0.y, acc[1]);
            acc[2] = fmaf(wc, e0.z, acc[2]); acc[3] = fmaf(wc, e0.w, acc[3]);
            acc[4] = fmaf(wc, e1.x, acc[4]); acc[5] = fmaf(wc, e1.y, acc[5]);
            acc[6] = fmaf(wc, e1.z, acc[6]); acc[7] = fmaf(wc, e1.w, acc[7]);
        }
        int f = m & 7;
        u32x4 p0, p1;
        #pragma unroll
        for (int e = 0; e < 4; ++e) { p0[e] = packsplit(acc[e]); p1[e] = packsplit(acc[4 + e]); }
        int g0i = k0 >> 2;
        *(u32x4*)(smem + 32768 + m * 256 + ((g0i ^ f) << 4))       = p0;
        *(u32x4*)(smem + 32768 + m * 256 + (((g0i + 1) ^ f) << 4)) = p1;
    }
    __syncthreads();

    f32x4 zero4 = {0.f, 0.f, 0.f, 0.f};
    f32x4 c0[4][4];
    #pragma unroll
    for (int mt = 0; mt < 4; ++mt)
        #pragma unroll
        for (int nn = 0; nn < 4; ++nn) c0[mt][nn] = zero4;

    #pragma unroll
    for (int ks = 0; ks < 2; ++ks) {
        half8 Ah[4], Al[4];
        #pragma unroll
        for (int mt = 0; mt < 4; ++mt) {
            int m = mt * 16 + lr, f = m & 7;
            const unsigned char* rb = smem + 32768 + m * 256;
            int gb2i = ks * 8 + 2 * q;
            u32x4 w0 = *(const u32x4*)(rb + (((gb2i)     ^ f) << 4));
            u32x4 w1 = *(const u32x4*)(rb + (((gb2i + 1) ^ f) << 4));
            unpackA(w0, w1, Ah[mt], Al[mt]);
        }
        #pragma unroll
        for (int nn = 0; nn < 4; ++nn) {
            int ntg = wv * 4 + nn;
            long boff = (long)((ks * 32 + ntg) * 64 + l) * 8;
            half8 Bh = *(const half8*)(fw0h + boff);
            half8 Bl = *(const half8*)(fw0l + boff);
            #pragma unroll
            for (int mt = 0; mt < 4; ++mt) {
                c0[mt][nn] = MFMA16(Ah[mt], Bh, c0[mt][nn]);
                c0[mt][nn] = MFMA16(Ah[mt], Bl, c0[mt][nn]);
                c0[mt][nn] = MFMA16(Al[mt], Bh, c0[mt][nn]);
            }
        }
    }

    uint32_t* h0b = h0pk + (size_t)m_blk * 32768;
    #pragma unroll
    for (int mt = 0; mt < 4; ++mt) {
        #pragma unroll
        for (int nn = 0; nn < 4; ++nn) {
            int ntg = wv * 4 + nn;
            int kstep = ntg >> 1;
            int klo = (ntg & 1) * 16 + lr;
            #pragma unroll
            for (int r = 0; r < 4; ++r) {
                int node = mt * 16 + q * 4 + r;
                float v = leaky(c0[mt][nn][r] + base_f[node * 512 + ntg * 16 + lr]);
                int sw = (((klo >> 2) ^ (node & 7)) << 2) + (klo & 3);
                h0b[kstep * 2048 + node * 32 + sw] = packsplit(v);   // cacheable -> L3
            }
        }
    }
}

// ---------------- k_l1: M=128 layer1 GEMM + fused layer2 ----------------
// LDS: [0,32768) A dbuf (2 x 16 KB: [half mb][64 rows][128 B]); [32768,36864) part

__global__ __launch_bounds__(512, 2) void k_l1(
    const uint32_t* __restrict__ h0pk,
    const _Float16* __restrict__ fw1h, const _Float16* __restrict__ fw1l,
    const float* __restrict__ fb1, const float* __restrict__ w2P,
    const float* __restrict__ fb2, float* __restrict__ out, int mblk_base)
{
    __shared__ __align__(16) unsigned char smem[36864];
    const int t = threadIdx.x, l = t & 63, wv = t >> 6;
    const int wm = wv >> 2, wn = wv & 3, q = l >> 4, lr = l & 15;
    const int mb0 = mblk_base + blockIdx.x * 2;
    const uint32_t* h0a = h0pk + (size_t)mb0 * 32768;
    const uint32_t* h0c = h0a + 32768;

    gl_lds16(h0a + t * 4, smem + t * 16);           // kk=0, mb0 half
    gl_lds16(h0c + t * 4, smem + 8192 + t * 16);    // kk=0, mb1 half

    f32x4 zero4 = {0.f, 0.f, 0.f, 0.f};
    f32x4 acc[4][8];
    #pragma unroll
    for (int mt = 0; mt < 4; ++mt)
        #pragma unroll
        for (int nt = 0; nt < 8; ++nt) acc[mt][nt] = zero4;

    for (int kk = 0; kk < 16; ++kk) {
        const int pb = kk & 1;
        __syncthreads();                 // A[kk] resident; other buffer free
        if (kk < 15) {
            gl_lds16(h0a + (kk + 1) * 2048 + t * 4,
                     smem + (pb ^ 1) * 16384 + t * 16);
            gl_lds16(h0c + (kk + 1) * 2048 + t * 4,
                     smem + (pb ^ 1) * 16384 + 8192 + t * 16);
        }

        half8 Ah[4], Al[4];
        #pragma unroll
        for (int mt = 0; mt < 4; ++mt) {
            int lrow = mt * 16 + lr, f = lrow & 7;
            const unsigned char* rb = smem + pb * 16384 + wm * 8192 + lrow * 128;
            u32x4 w0 = *(const u32x4*)(rb + (((2 * q)     ^ f) << 4));
            u32x4 w1 = *(const u32x4*)(rb + (((2 * q + 1) ^ f) << 4));
            unpackA(w0, w1, Ah[mt], Al[mt]);
        }
        #pragma unroll
        for (int nt = 0; nt < 8; ++nt) {
            long boff = (long)((kk * 32 + wn * 8 + nt) * 64 + l) * 8;
            half8 Bh = *(const half8*)(fw1h + boff);
            half8 Bl = *(const half8*)(fw1l + boff);
            #pragma unroll
            for (int mt = 0; mt < 4; ++mt) {
                acc[mt][nt] = MFMA16(Ah[mt], Bh, acc[mt][nt]);
                acc[mt][nt] = MFMA16(Ah[mt], Bl, acc[mt][nt]);
                acc[mt][nt] = MFMA16(Al[mt], Bh, acc[mt][nt]);
            }
        }
    }

    // h1 = leaky(acc+fb1); fused layer2 partial dots; reduce lr then wn
    float* part = (float*)(smem + 32768);   // [wm 2][wn 4][node 64][d 2]
    #pragma unroll
    for (int mt = 0; mt < 4; ++mt) {
        float s0[4] = {0.f,0.f,0.f,0.f}, s1[4] = {0.f,0.f,0.f,0.f};
        #pragma unroll
        for (int nt = 0; nt < 8; ++nt) {
            int col = wn * 128 + nt * 16 + lr;
            float bb = fb1[col];
            #pragma unroll
            for (int r = 0; r < 4; ++r) {
                int node = mt * 16 + q * 4 + r;
                float h1 = leaky(acc[mt][nt][r] + bb);
                float2 w2 = *(const float2*)(w2P + (((size_t)node * 512 + col) << 1));
                s0[r] = fmaf(h1, w2.x, s0[r]);
                s1[r] = fmaf(h1, w2.y, s1[r]);
            }
        }
        #pragma unroll
        for (int r = 0; r < 4; ++r) {
            s0[r] += __shfl_xor(s0[r], 1, 64); s0[r] += __shfl_xor(s0[r], 2, 64);
            s0[r] += __shfl_xor(s0[r], 4, 64); s0[r] += __shfl_xor(s0[r], 8, 64);
            s1[r] += __shfl_xor(s1[r], 1, 64); s1[r] += __shfl_xor(s1[r], 2, 64);
            s1[r] += __shfl_xor(s1[r], 4, 64); s1[r] += __shfl_xor(s1[r], 8, 64);
            if (lr == 0) {
                int node = mt * 16 + q * 4 + r;
                part[wm * 512 + wn * 128 + node * 2 + 0] = s0[r];
                part[wm * 512 + wn * 128 + node * 2 + 1] = s1[r];
            }
        }
    }
    __syncthreads();
    if (t < 256) {
        int wmx = t >> 7, rem = t & 127;
        float s = part[wmx * 512 + rem] + part[wmx * 512 + 128 + rem]
                + part[wmx * 512 + 256 + rem] + part[wmx * 512 + 384 + rem];
        out[(mb0 + wmx) * 128 + rem] = s + fb2[rem];
    }
}

// ---------------- launch ----------------

extern "C" void kernel_launch(void* const* d_in, const int* in_sizes, int n_in,
                              void* d_out, int out_size, void* d_ws, size_t ws_size,
                              hipStream_t stream)
{
    const float* samples    = (const float*)d_in[0];
    const float* graphs     = (const float*)d_in[1];
    const float* embeddings = (const float*)d_in[3];
    const float* w          = (const float*)d_in[4];
    const float* g_w0 = (const float*)d_in[5];
    const float* g_b0 = (const float*)d_in[6];
    const float* g_w1 = (const float*)d_in[7];
    const float* g_b1 = (const float*)d_in[8];
    const float* g_w2 = (const float*)d_in[9];
    const float* g_b2 = (const float*)d_in[10];
    const float* f_w0 = (const float*)d_in[11];
    const float* f_b0 = (const float*)d_in[12];
    const float* f_w1 = (const float*)d_in[13];
    const float* f_b1 = (const float*)d_in[14];
    const float* f_w2 = (const float*)d_in[15];
    const float* f_b2 = (const float*)d_in[16];
    float* out = (float*)d_out;

    float* ws     = (float*)d_ws;
    float* base_g = ws;                    // 32768 f
    float* base_f = ws + 32768;            // 32768 f
    float* w2P    = ws + 65536;            // 65536 f
    float* emb_s  = ws + 131072;           // 1048576 f
    _Float16* f16b = (_Float16*)(ws + 1179648);
    _Float16* fw1h = f16b;                 // 262144 h
    _Float16* fw1l = f16b + 262144;
    _Float16* fw0h = f16b + 524288;        // 32768 h
    _Float16* fw0l = f16b + 557056;
    _Float16* gw1h = f16b + 589824;        // 262144 h
    _Float16* gw1l = f16b + 851968;
    _Float16* gw2h = f16b + 1114112;       // 32768 h
    _Float16* gw2l = f16b + 1146880;       // end: 1179648 h (= 589824 floats)
    uint32_t* h0pk = (uint32_t*)(ws + 1769472);

    size_t ws_u32 = ws_size / 4;
    size_t avail  = (ws_u32 > 1769472) ? ws_u32 - 1769472 : 0;
    int chunk = (int)(avail / 32768) & ~1;      // even # of m-blocks
    if (chunk > 2048) chunk = 2048;
    if (chunk < 2) chunk = 2;
    int nrounds = (2048 + chunk - 1) / chunk;

    hipLaunchKernelGGL(k_base, dim3(256), dim3(256), 0, stream,
                       embeddings, g_w0, g_b0, f_w0, f_b0, base_g, base_f);
    hipLaunchKernelGGL(k_w2p, dim3(256), dim3(256), 0, stream, f_w2, w2P);
    hipLaunchKernelGGL(k_splitw, dim3(288), dim3(256), 0, stream,
                       f_w0, f_w1, g_w1, g_w2,
                       fw0h, fw0l, fw1h, fw1l, gw1h, gw1l, gw2h, gw2l);
    hipLaunchKernelGGL(k_gmlp, dim3(256), dim3(512), 0, stream,
                       samples, g_w0, base_g, g_b1, g_b2,
                       gw1h, gw1l, gw2h, gw2l, emb_s);

    for (int r = 0; r < nrounds; ++r) {
        int base = r * chunk;
        int n = (2048 - base < chunk) ? (2048 - base) : chunk;
        hipLaunchKernelGGL(k_h0, dim3(n), dim3(512), 0, stream,
                           graphs, w, emb_s, base_f, fw0h, fw0l,
                           h0pk - (size_t)base * 32768, base);
        hipLaunchKernelGGL(k_l1, dim3(n / 2), dim3(512), 0, stream,
                           h0pk - (size_t)base * 32768, fw1h, fw1l,
                           f_b1, w2P, f_b2, out, base);
    }
}

// Round 7
// 463.025 us; speedup vs baseline: 3.7952x; 1.0999x over previous
//
#include <hip/hip_runtime.h>
#include <stdint.h>

// N=64, D=128, EMB=64, OUTG=64, A=512, B=256, G=8
// group_mask[i,j] = (j//2 == i).
//
// Pipeline (all heavy GEMMs on split-f16 MFMA: a=a_hi+a_lo,
// a*b ~= AhBh + AhBl + AlBh, fp32 acc):
//   k_gmlp: g-MLP per batch b (MFMA layer1+layer2)
//   k_h0:   per (b,g): aggr fp32 -> layer0 MFMA + base_f -> leaky -> packed u32
//           [f16hi|f16lo], pre-swizzled, cacheable store (L3-resident)
//   k_l1 v3: per m-blk PAIR (M=128): wave owns a 64-col n-slice (no B duplication),
//           A via global_load_lds dbuf, fused bias/leaky/layer2 epilogue, setprio.

typedef _Float16 half8 __attribute__((ext_vector_type(8)));
typedef float    f32x4 __attribute__((ext_vector_type(4)));
typedef uint32_t u32x4 __attribute__((ext_vector_type(4)));

#define MFMA16(a, b, c) __builtin_amdgcn_mfma_f32_16x16x32_f16(a, b, c, 0, 0, 0)

__device__ __forceinline__ float leaky(float v) { return v >= 0.f ? v : 0.01f * v; }

__device__ __forceinline__ uint32_t packsplit(float v) {
    _Float16 hi = (_Float16)v;
    _Float16 lo = (_Float16)(v - (float)hi);
    union { _Float16 f; unsigned short u; } a, c;
    a.f = hi; c.f = lo;
    return (uint32_t)a.u | ((uint32_t)c.u << 16);
}

__device__ __forceinline__ void unpackA(u32x4 w0, u32x4 w1, half8& Ah, half8& Al) {
    union { u32x4 u; half8 h; } ah, al;
    ah.u[0] = (w0[0] & 0xffffu) | (w0[1] << 16);
    ah.u[1] = (w0[2] & 0xffffu) | (w0[3] << 16);
    ah.u[2] = (w1[0] & 0xffffu) | (w1[1] << 16);
    ah.u[3] = (w1[2] & 0xffffu) | (w1[3] << 16);
    al.u[0] = (w0[0] >> 16) | (w0[1] & 0xffff0000u);
    al.u[1] = (w0[2] >> 16) | (w0[3] & 0xffff0000u);
    al.u[2] = (w1[0] >> 16) | (w1[1] & 0xffff0000u);
    al.u[3] = (w1[2] >> 16) | (w1[3] & 0xffff0000u);
    Ah = ah.h; Al = al.h;
}

__device__ __forceinline__ void gl_lds16(const void* g, void* l) {
    __builtin_amdgcn_global_load_lds(
        (const __attribute__((address_space(1))) unsigned int*)g,
        (__attribute__((address_space(3))) unsigned int*)l, 16, 0, 0);
}

// ---------------- prep kernels ----------------

__global__ void k_base(const float* __restrict__ emb,
                       const float* __restrict__ gw0, const float* __restrict__ gb0,
                       const float* __restrict__ fw0, const float* __restrict__ fb0,
                       float* __restrict__ base_g, float* __restrict__ base_f)
{
    int blk = blockIdx.x;            // 256 blocks
    int n     = blk >> 2;
    int half  = (blk >> 1) & 1;
    int which = blk & 1;
    int c = half * 256 + threadIdx.x;
    const float* W    = which ? fw0 : gw0;
    const float* bias = which ? fb0 : gb0;
    float* dst        = which ? base_f : base_g;
    int off           = which ? 64 : 128;
    const float* e = emb + n * 64;
    float acc = bias[c];
    #pragma unroll 8
    for (int k = 0; k < 64; ++k)
        acc = fmaf(e[k], W[(off + k) * 512 + c], acc);
    dst[n * 512 + c] = acc;
}

// w2P[node][a][d] = fw2[a][2*node+d]
__global__ void k_w2p(const float* __restrict__ fw2, float* __restrict__ w2P)
{
    int tid = blockIdx.x * 256 + threadIdx.x;   // grid 256 -> 65536
    int c = tid >> 9, a = tid & 511;            // c = 2*node+d
    int node = c >> 1, d = c & 1;
    w2P[(node * 512 + a) * 2 + d] = fw2[a * 128 + c];
}

// Fragment-linear f16 hi/lo splits:
//  fw1/gw1 (512x512): frag[(kstep*32+ntg)*64+l][j] = W[kstep*32+(l>>4)*8+j][ntg*16+(l&15)]
//  fw0 rows 0..63:    frag[(kstep*32+ntg)*64+l][j] (kstep 0..1)
//  gw2 (512x64):      frag[(kstep*4+ntg)*64+l][j]  = gw2[kstep*32+(l>>4)*8+j][ntg*16+(l&15)]
__global__ void k_splitw(const float* __restrict__ fw0, const float* __restrict__ fw1,
                         const float* __restrict__ gw1, const float* __restrict__ gw2,
                         _Float16* __restrict__ fw0h, _Float16* __restrict__ fw0l,
                         _Float16* __restrict__ fw1h, _Float16* __restrict__ fw1l,
                         _Float16* __restrict__ gw1h, _Float16* __restrict__ gw1l,
                         _Float16* __restrict__ gw2h, _Float16* __restrict__ gw2l)
{
    int tid = blockIdx.x * 256 + threadIdx.x;
    if (blockIdx.x < 128) {                       // fw1
        int l = tid & 63, grp = tid >> 6;
        int kstep = grp >> 5, ntg = grp & 31;
        #pragma unroll
        for (int j = 0; j < 8; ++j) {
            int k = kstep * 32 + (l >> 4) * 8 + j;
            int n = ntg * 16 + (l & 15);
            float v = fw1[k * 512 + n];
            _Float16 h = (_Float16)v;
            fw1h[tid * 8 + j] = h;
            fw1l[tid * 8 + j] = (_Float16)(v - (float)h);
        }
    } else if (blockIdx.x < 144) {                // fw0 rows 0..63
        int t2 = tid - 32768;
        int l = t2 & 63, grp = t2 >> 6;
        int kstep = grp >> 5, ntg = grp & 31;
        #pragma unroll
        for (int j = 0; j < 8; ++j) {
            int k = kstep * 32 + (l >> 4) * 8 + j;
            int n = ntg * 16 + (l & 15);
            float v = fw0[k * 512 + n];
            _Float16 h = (_Float16)v;
            fw0h[t2 * 8 + j] = h;
            fw0l[t2 * 8 + j] = (_Float16)(v - (float)h);
        }
    } else if (blockIdx.x < 272) {                // gw1
        int t4 = tid - 36864;
        int l = t4 & 63, grp = t4 >> 6;
        int kstep = grp >> 5, ntg = grp & 31;
        #pragma unroll
        for (int j = 0; j < 8; ++j) {
            int k = kstep * 32 + (l >> 4) * 8 + j;
            int n = ntg * 16 + (l & 15);
            float v = gw1[k * 512 + n];
            _Float16 h = (_Float16)v;
            gw1h[t4 * 8 + j] = h;
            gw1l[t4 * 8 + j] = (_Float16)(v - (float)h);
        }
    } else {                                      // gw2
        int t3 = tid - 69632;                     // 0..4095
        int l = t3 & 63, grp = t3 >> 6;           // grp 0..63
        int kstep = grp >> 2, ntg = grp & 3;
        #pragma unroll
        for (int j = 0; j < 8; ++j) {
            int k = kstep * 32 + (l >> 4) * 8 + j;
            int n = ntg * 16 + (l & 15);
            float v = gw2[k * 64 + n];
            _Float16 h = (_Float16)v;
            gw2h[t3 * 8 + j] = h;
            gw2l[t3 * 8 + j] = (_Float16)(v - (float)h);
        }
    }
}

// ---------------- k_gmlp: g-MLP on MFMA (unchanged) ----------------
// One block per batch b (256 blocks, 512 thr, 8 waves).
// LDS (80 KB): [0,16K) h0g stage dbuf (2 x 8 KB); [16K,80K) h1 packed (8 ksteps x 8 KB)

__global__ __launch_bounds__(512, 2) void k_gmlp(
    const float* __restrict__ samples, const float* __restrict__ gw0,
    const float* __restrict__ base_g, const float* __restrict__ gb1,
    const float* __restrict__ gb2,
    const _Float16* __restrict__ gw1h, const _Float16* __restrict__ gw1l,
    const _Float16* __restrict__ gw2h, const _Float16* __restrict__ gw2l,
    float* __restrict__ emb_s)
{
    __shared__ __align__(16) unsigned char smem[81920];
    const int t = threadIdx.x, l = t & 63, wv = t >> 6;
    const int q = l >> 4, lr = l & 15;
    const int b = blockIdx.x;

    f32x4 zero4 = {0.f, 0.f, 0.f, 0.f};
    f32x4 acc[4][4];
    #pragma unroll
    for (int mt = 0; mt < 4; ++mt)
        #pragma unroll
        for (int nt = 0; nt < 4; ++nt) acc[mt][nt] = zero4;

    auto stage = [&](int kk, int bq) {
        #pragma unroll
        for (int it = 0; it < 4; ++it) {
            int n = it * 16 + (t >> 5);
            int c = kk * 32 + (t & 31);
            float s0 = samples[b * 128 + 2 * n];
            float s1 = samples[b * 128 + 2 * n + 1];
            float v = fmaf(s0, gw0[(2 * n) * 512 + c],
                      fmaf(s1, gw0[(2 * n + 1) * 512 + c], base_g[n * 512 + c]));
            v = leaky(v);
            int kl = t & 31;
            int sw = (((kl >> 2) ^ (n & 7)) << 2) | (kl & 3);
            *(uint32_t*)(smem + bq * 8192 + n * 128 + sw * 4) = packsplit(v);
        }
    };

    stage(0, 0);
    for (int kk = 0; kk < 16; ++kk) {
        const int pb = kk & 1;
        __syncthreads();
        if (kk < 15) stage(kk + 1, pb ^ 1);

        half8 Ah[4], Al[4];
        #pragma unroll
        for (int mt = 0; mt < 4; ++mt) {
            int row = mt * 16 + lr, f = row & 7;
            const unsigned char* rb = smem + pb * 8192 + row * 128;
            u32x4 w0 = *(const u32x4*)(rb + (((2 * q) ^ f) << 4));
            u32x4 w1 = *(const u32x4*)(rb + (((2 * q + 1) ^ f) << 4));
            unpackA(w0, w1, Ah[mt], Al[mt]);
        }
        #pragma unroll
        for (int nt = 0; nt < 4; ++nt) {
            int ntg = wv * 4 + nt;
            long boff = (long)((kk * 32 + ntg) * 64 + l) * 8;
            half8 Bh = *(const half8*)(gw1h + boff);
            half8 Bl = *(const half8*)(gw1l + boff);
            #pragma unroll
            for (int mt = 0; mt < 4; ++mt) {
                acc[mt][nt] = MFMA16(Ah[mt], Bh, acc[mt][nt]);
                acc[mt][nt] = MFMA16(Ah[mt], Bl, acc[mt][nt]);
                acc[mt][nt] = MFMA16(Al[mt], Bh, acc[mt][nt]);
            }
        }
    }

    const int mt2 = wv >> 1;
    f32x4 acc2[2] = {zero4, zero4};
    #pragma unroll
    for (int half = 0; half < 2; ++half) {
        __syncthreads();
        if ((wv >> 2) == half) {
            #pragma unroll
            for (int nt = 0; nt < 4; ++nt) {
                int col = wv * 64 + nt * 16 + lr;
                float bb = gb1[col];
                int ksl = (col >> 5) - half * 8;
                int kl = col & 31;
                #pragma unroll
                for (int mt = 0; mt < 4; ++mt)
                    #pragma unroll
                    for (int r = 0; r < 4; ++r) {
                        int row = mt * 16 + q * 4 + r;
                        float v = leaky(acc[mt][nt][r] + bb);
                        int sw = (((kl >> 2) ^ (row & 7)) << 2) | (kl & 3);
                        *(uint32_t*)(smem + 16384 + ksl * 8192 + row * 128 + sw * 4)
                            = packsplit(v);
                    }
            }
        }
        __syncthreads();
        #pragma unroll
        for (int ks = 0; ks < 8; ++ks) {
            int kstep = half * 8 + ks;
            int row = mt2 * 16 + lr, f = row & 7;
            const unsigned char* rb = smem + 16384 + ks * 8192 + row * 128;
            u32x4 w0 = *(const u32x4*)(rb + (((2 * q) ^ f) << 4));
            u32x4 w1 = *(const u32x4*)(rb + (((2 * q + 1) ^ f) << 4));
            half8 Ah2, Al2;
            unpackA(w0, w1, Ah2, Al2);
            #pragma unroll
            for (int nt = 0; nt < 2; ++nt) {
                int ntg = (wv & 1) * 2 + nt;
                long boff = (long)((kstep * 4 + ntg) * 64 + l) * 8;
                half8 Bh = *(const half8*)(gw2h + boff);
                half8 Bl = *(const half8*)(gw2l + boff);
                acc2[nt] = MFMA16(Ah2, Bh, acc2[nt]);
                acc2[nt] = MFMA16(Ah2, Bl, acc2[nt]);
                acc2[nt] = MFMA16(Al2, Bh, acc2[nt]);
            }
        }
    }
    #pragma unroll
    for (int nt = 0; nt < 2; ++nt) {
        int col = ((wv & 1) * 2 + nt) * 16 + lr;
        float bb = gb2[col];
        #pragma unroll
        for (int r = 0; r < 4; ++r) {
            int node = mt2 * 16 + q * 4 + r;
            emb_s[b * 4096 + node * 64 + col] = acc2[nt][r] + bb;
        }
    }
}

// ---------------- k_h0: aggr + layer0 -> packed h0 (unchanged) ----------------
// h0pk (u32): [m_blk][kstep 16][row 64][32], pre-swizzled:
//   u32 idx in row line = ((klocal>>2) ^ (row&7))*4 + (klocal&3)

__global__ __launch_bounds__(512, 4) void k_h0(
    const float* __restrict__ graphs, const float* __restrict__ w,
    const float* __restrict__ emb_s, const float* __restrict__ base_f,
    const _Float16* __restrict__ fw0h, const _Float16* __restrict__ fw0l,
    uint32_t* __restrict__ h0pk, int mblk_base)
{
    __shared__ __align__(16) unsigned char smem[49152];
    float* s_emb  = (float*)smem;            // 16 KB
    float* s_wadj = (float*)(smem + 16384);  // 16 KB; A0 packed at +32768
    const int t = threadIdx.x, l = t & 63, wv = t >> 6;
    const int q = l >> 4, lr = l & 15;
    const int m_blk = mblk_base + blockIdx.x;
    const int b = m_blk >> 3, g = m_blk & 7;

    {
        const float* eb = emb_s + b * 4096;
        const float* gb = graphs + g * 4096;
        int idx = t * 8;
        *(float4*)(s_emb + idx)     = *(const float4*)(eb + idx);
        *(float4*)(s_emb + idx + 4) = *(const float4*)(eb + idx + 4);
        float4 g0 = *(const float4*)(gb + idx);
        float4 w0 = *(const float4*)(w + idx);
        float4 m0; m0.x = g0.x*w0.x; m0.y = g0.y*w0.y; m0.z = g0.z*w0.z; m0.w = g0.w*w0.w;
        *(float4*)(s_wadj + idx) = m0;
        float4 g1 = *(const float4*)(gb + idx + 4);
        float4 w1 = *(const float4*)(w + idx + 4);
        float4 m1; m1.x = g1.x*w1.x; m1.y = g1.y*w1.y; m1.z = g1.z*w1.z; m1.w = g1.w*w1.w;
        *(float4*)(s_wadj + idx + 4) = m1;
    }
    __syncthreads();

    {
        int m = t >> 3, k0 = (t & 7) * 8;
        float acc[8] = {0.f,0.f,0.f,0.f,0.f,0.f,0.f,0.f};
        for (int j = 0; j < 64; ++j) {
            float wc = s_wadj[j * 64 + m];
            float4 e0 = *(const float4*)(s_emb + j * 64 + k0);
            float4 e1 = *(const float4*)(s_emb + j * 64 + k0 + 4);
            acc[0] = fmaf(wc, e0.x, acc[0]); acc[1] = fmaf(wc, e0.y, acc[1]);
            acc[2] = fmaf(wc, e0.z, acc[2]); acc[3] = fmaf(wc, e0.w, acc[3]);
            acc[4] = fmaf(wc, e1.x, acc[4]); acc[5] = fmaf(wc, e1.y, acc[5]);
            acc[6] = fmaf(wc, e1.z, acc[6]); acc[7] = fmaf(wc, e1.w, acc[7]);
        }
        int f = m & 7;
        u32x4 p0, p1;
        #pragma unroll
        for (int e = 0; e < 4; ++e) { p0[e] = packsplit(acc[e]); p1[e] = packsplit(acc[4 + e]); }
        int g0i = k0 >> 2;
        *(u32x4*)(smem + 32768 + m * 256 + ((g0i ^ f) << 4))       = p0;
        *(u32x4*)(smem + 32768 + m * 256 + (((g0i + 1) ^ f) << 4)) = p1;
    }
    __syncthreads();

    f32x4 zero4 = {0.f, 0.f, 0.f, 0.f};
    f32x4 c0[4][4];
    #pragma unroll
    for (int mt = 0; mt < 4; ++mt)
        #pragma unroll
        for (int nn = 0; nn < 4; ++nn) c0[mt][nn] = zero4;

    #pragma unroll
    for (int ks = 0; ks < 2; ++ks) {
        half8 Ah[4], Al[4];
        #pragma unroll
        for (int mt = 0; mt < 4; ++mt) {
            int m = mt * 16 + lr, f = m & 7;
            const unsigned char* rb = smem + 32768 + m * 256;
            int gb2i = ks * 8 + 2 * q;
            u32x4 w0 = *(const u32x4*)(rb + (((gb2i)     ^ f) << 4));
            u32x4 w1 = *(const u32x4*)(rb + (((gb2i + 1) ^ f) << 4));
            unpackA(w0, w1, Ah[mt], Al[mt]);
        }
        #pragma unroll
        for (int nn = 0; nn < 4; ++nn) {
            int ntg = wv * 4 + nn;
            long boff = (long)((ks * 32 + ntg) * 64 + l) * 8;
            half8 Bh = *(const half8*)(fw0h + boff);
            half8 Bl = *(const half8*)(fw0l + boff);
            #pragma unroll
            for (int mt = 0; mt < 4; ++mt) {
                c0[mt][nn] = MFMA16(Ah[mt], Bh, c0[mt][nn]);
                c0[mt][nn] = MFMA16(Ah[mt], Bl, c0[mt][nn]);
                c0[mt][nn] = MFMA16(Al[mt], Bh, c0[mt][nn]);
            }
        }
    }

    uint32_t* h0b = h0pk + (size_t)m_blk * 32768;
    #pragma unroll
    for (int mt = 0; mt < 4; ++mt) {
        #pragma unroll
        for (int nn = 0; nn < 4; ++nn) {
            int ntg = wv * 4 + nn;
            int kstep = ntg >> 1;
            int klo = (ntg & 1) * 16 + lr;
            #pragma unroll
            for (int r = 0; r < 4; ++r) {
                int node = mt * 16 + q * 4 + r;
                float v = leaky(c0[mt][nn][r] + base_f[node * 512 + ntg * 16 + lr]);
                int sw = (((klo >> 2) ^ (node & 7)) << 2) + (klo & 3);
                h0b[kstep * 2048 + node * 32 + sw] = packsplit(v);
            }
        }
    }
}

// ---------------- k_l1 v3: M=128, wave-per-n-slice, fused layer2 ----------------
// LDS: [0,32768) A dbuf (2 x 16 KB: rows 0..127 x 128 B); [32768,40960) part

__global__ __launch_bounds__(512, 2) void k_l1(
    const uint32_t* __restrict__ h0pk,
    const _Float16* __restrict__ fw1h, const _Float16* __restrict__ fw1l,
    const float* __restrict__ fb1, const float* __restrict__ w2P,
    const float* __restrict__ fb2, float* __restrict__ out, int mblk_base)
{
    __shared__ __align__(16) unsigned char smem[40960];
    const int t = threadIdx.x, l = t & 63, wv = t >> 6;
    const int q = l >> 4, lr = l & 15;
    const int mb0 = mblk_base + blockIdx.x * 2;
    const uint32_t* h0a = h0pk + (size_t)mb0 * 32768;
    const uint32_t* h0c = h0a + 32768;

    gl_lds16(h0a + t * 4, smem + t * 16);           // kk=0, rows 0..63
    gl_lds16(h0c + t * 4, smem + 8192 + t * 16);    // kk=0, rows 64..127

    f32x4 zero4 = {0.f, 0.f, 0.f, 0.f};
    f32x4 acc[8][4];
    #pragma unroll
    for (int mt = 0; mt < 8; ++mt)
        #pragma unroll
        for (int nt = 0; nt < 4; ++nt) acc[mt][nt] = zero4;

    for (int kk = 0; kk < 16; ++kk) {
        const int pb = kk & 1;
        __syncthreads();                 // A[kk] resident; buf[pb^1] free
        if (kk < 15) {
            gl_lds16(h0a + (kk + 1) * 2048 + t * 4,
                     smem + (pb ^ 1) * 16384 + t * 16);
            gl_lds16(h0c + (kk + 1) * 2048 + t * 4,
                     smem + (pb ^ 1) * 16384 + 8192 + t * 16);
        }

        // B for this wave's 4 n-tiles (loaded once per kk, live across both halves)
        half8 Bh[4], Bl[4];
        #pragma unroll
        for (int nt = 0; nt < 4; ++nt) {
            long boff = (long)((kk * 32 + wv * 4 + nt) * 64 + l) * 8;
            Bh[nt] = *(const half8*)(fw1h + boff);
            Bl[nt] = *(const half8*)(fw1l + boff);
        }

        #pragma unroll
        for (int hf = 0; hf < 2; ++hf) {
            half8 Ah[4], Al[4];
            #pragma unroll
            for (int mq = 0; mq < 4; ++mq) {
                int row = (hf * 4 + mq) * 16 + lr;      // 0..127 contiguous in LDS
                int f = row & 7;
                const unsigned char* rb = smem + pb * 16384 + row * 128;
                u32x4 w0 = *(const u32x4*)(rb + (((2 * q)     ^ f) << 4));
                u32x4 w1 = *(const u32x4*)(rb + (((2 * q + 1) ^ f) << 4));
                unpackA(w0, w1, Ah[mq], Al[mq]);
            }
            __builtin_amdgcn_s_setprio(1);
            #pragma unroll
            for (int nt = 0; nt < 4; ++nt)
                #pragma unroll
                for (int mq = 0; mq < 4; ++mq) {
                    int mt = hf * 4 + mq;
                    acc[mt][nt] = MFMA16(Ah[mq], Bh[nt], acc[mt][nt]);
                    acc[mt][nt] = MFMA16(Ah[mq], Bl[nt], acc[mt][nt]);
                    acc[mt][nt] = MFMA16(Al[mq], Bh[nt], acc[mt][nt]);
                }
            __builtin_amdgcn_s_setprio(0);
        }
    }

    // h1 = leaky(acc+fb1); fused layer2 partial dots over this wave's 64 cols
    float* part = (float*)(smem + 32768);   // [wv 8][row 128][d 2]
    #pragma unroll
    for (int mt = 0; mt < 8; ++mt) {
        float s0[4] = {0.f,0.f,0.f,0.f}, s1[4] = {0.f,0.f,0.f,0.f};
        #pragma unroll
        for (int nt = 0; nt < 4; ++nt) {
            int col = wv * 64 + nt * 16 + lr;
            float bb = fb1[col];
            #pragma unroll
            for (int r = 0; r < 4; ++r) {
                int row = mt * 16 + q * 4 + r;
                int node = row & 63;
                float h1 = leaky(acc[mt][nt][r] + bb);
                float2 w2 = *(const float2*)(w2P + (((size_t)node * 512 + col) << 1));
                s0[r] = fmaf(h1, w2.x, s0[r]);
                s1[r] = fmaf(h1, w2.y, s1[r]);
            }
        }
        #pragma unroll
        for (int r = 0; r < 4; ++r) {
            s0[r] += __shfl_xor(s0[r], 1, 64); s0[r] += __shfl_xor(s0[r], 2, 64);
            s0[r] += __shfl_xor(s0[r], 4, 64); s0[r] += __shfl_xor(s0[r], 8, 64);
            s1[r] += __shfl_xor(s1[r], 1, 64); s1[r] += __shfl_xor(s1[r], 2, 64);
            s1[r] += __shfl_xor(s1[r], 4, 64); s1[r] += __shfl_xor(s1[r], 8, 64);
            if (lr == 0) {
                int row = mt * 16 + q * 4 + r;
                part[wv * 256 + row * 2 + 0] = s0[r];
                part[wv * 256 + row * 2 + 1] = s1[r];
            }
        }
    }
    __syncthreads();
    if (t < 256) {
        int row = t >> 1, d = t & 1;
        float s = 0.f;
        #pragma unroll
        for (int v8 = 0; v8 < 8; ++v8) s += part[v8 * 256 + row * 2 + d];
        int node = row & 63;
        out[(mb0 + (row >> 6)) * 128 + node * 2 + d] = s + fb2[node * 2 + d];
    }
}

// ---------------- launch ----------------

extern "C" void kernel_launch(void* const* d_in, const int* in_sizes, int n_in,
                              void* d_out, int out_size, void* d_ws, size_t ws_size,
                              hipStream_t stream)
{
    const float* samples    = (const float*)d_in[0];
    const float* graphs     = (const float*)d_in[1];
    const float* embeddings = (const float*)d_in[3];
    const float* w          = (const float*)d_in[4];
    const float* g_w0 = (const float*)d_in[5];
    const float* g_b0 = (const float*)d_in[6];
    const float* g_w1 = (const float*)d_in[7];
    const float* g_b1 = (const float*)d_in[8];
    const float* g_w2 = (const float*)d_in[9];
    const float* g_b2 = (const float*)d_in[10];
    const float* f_w0 = (const float*)d_in[11];
    const float* f_b0 = (const float*)d_in[12];
    const float* f_w1 = (const float*)d_in[13];
    const float* f_b1 = (const float*)d_in[14];
    const float* f_w2 = (const float*)d_in[15];
    const float* f_b2 = (const float*)d_in[16];
    float* out = (float*)d_out;

    float* ws     = (float*)d_ws;
    float* base_g = ws;                    // 32768 f
    float* base_f = ws + 32768;            // 32768 f
    float* w2P    = ws + 65536;            // 65536 f
    float* emb_s  = ws + 131072;           // 1048576 f
    _Float16* f16b = (_Float16*)(ws + 1179648);
    _Float16* fw1h = f16b;                 // 262144 h
    _Float16* fw1l = f16b + 262144;
    _Float16* fw0h = f16b + 524288;        // 32768 h
    _Float16* fw0l = f16b + 557056;
    _Float16* gw1h = f16b + 589824;        // 262144 h
    _Float16* gw1l = f16b + 851968;
    _Float16* gw2h = f16b + 1114112;       // 32768 h
    _Float16* gw2l = f16b + 1146880;       // end: 1179648 h (= 589824 floats)
    uint32_t* h0pk = (uint32_t*)(ws + 1769472);

    size_t ws_u32 = ws_size / 4;
    size_t avail  = (ws_u32 > 1769472) ? ws_u32 - 1769472 : 0;
    int chunk = (int)(avail / 32768) & ~1;      // even # of m-blocks
    if (chunk > 2048) chunk = 2048;
    if (chunk < 2) chunk = 2;
    int nrounds = (2048 + chunk - 1) / chunk;

    hipLaunchKernelGGL(k_base, dim3(256), dim3(256), 0, stream,
                       embeddings, g_w0, g_b0, f_w0, f_b0, base_g, base_f);
    hipLaunchKernelGGL(k_w2p, dim3(256), dim3(256), 0, stream, f_w2, w2P);
    hipLaunchKernelGGL(k_splitw, dim3(288), dim3(256), 0, stream,
                       f_w0, f_w1, g_w1, g_w2,
                       fw0h, fw0l, fw1h, fw1l, gw1h, gw1l, gw2h, gw2l);
    hipLaunchKernelGGL(k_gmlp, dim3(256), dim3(512), 0, stream,
                       samples, g_w0, base_g, g_b1, g_b2,
                       gw1h, gw1l, gw2h, gw2l, emb_s);

    for (int r = 0; r < nrounds; ++r) {
        int base = r * chunk;
        int n = (2048 - base < chunk) ? (2048 - base) : chunk;
        hipLaunchKernelGGL(k_h0, dim3(n), dim3(512), 0, stream,
                           graphs, w, emb_s, base_f, fw0h, fw0l,
                           h0pk - (size_t)base * 32768, base);
        hipLaunchKernelGGL(k_l1, dim3(n / 2), dim3(512), 0, stream,
                           h0pk - (size_t)base * 32768, fw1h, fw1l,
                           f_b1, w2P, f_b2, out, base);
    }
}

// Round 8
// 421.328 us; speedup vs baseline: 4.1708x; 1.0990x over previous
//
#include <hip/hip_runtime.h>
#include <stdint.h>

// N=64, D=128, EMB=64, OUTG=64, A=512, B=256, G=8
// group_mask[i,j] = (j//2 == i).
//
// k_f2: FULLY fused f-MLP per (b,g) block (1024 thr, 16 waves, 80 KB LDS):
//   stage emb_s[b]+wadj -> aggr fp32 -> packed A0 frags (LDS)
//   2 super-chunks of 256 h0-cols:
//     layer0 MFMA (K=64, fw0 frags from L2) -> +base_f/leaky -> h0 two-plane
//     f16 hi/lo in LDS (granule-XOR swizzled) -> 8 barrier-free layer1 K-steps
//     (fw1 frags streamed from L2, fully L2-resident: only ~2 MB of weights)
//   epilogue: +fb1/leaky -> fused layer2 partial dots -> LDS reduce -> out.
// No h0 global round-trip (round 7 paid 256 MB write + 148 MB fetch for it).
// fp16-split x3 MFMA: a = a_hi+a_lo; a*b ~= AhBh + AhBl + AlBh (fp32 acc).

typedef _Float16 half8 __attribute__((ext_vector_type(8)));
typedef float    f32x4 __attribute__((ext_vector_type(4)));
typedef uint32_t u32x4 __attribute__((ext_vector_type(4)));

#define MFMA16(a, b, c) __builtin_amdgcn_mfma_f32_16x16x32_f16(a, b, c, 0, 0, 0)

__device__ __forceinline__ float leaky(float v) { return v >= 0.f ? v : 0.01f * v; }

__device__ __forceinline__ uint32_t packsplit(float v) {
    _Float16 hi = (_Float16)v;
    _Float16 lo = (_Float16)(v - (float)hi);
    union { _Float16 f; unsigned short u; } a, c;
    a.f = hi; c.f = lo;
    return (uint32_t)a.u | ((uint32_t)c.u << 16);
}

__device__ __forceinline__ void unpackA(u32x4 w0, u32x4 w1, half8& Ah, half8& Al) {
    union { u32x4 u; half8 h; } ah, al;
    ah.u[0] = (w0[0] & 0xffffu) | (w0[1] << 16);
    ah.u[1] = (w0[2] & 0xffffu) | (w0[3] << 16);
    ah.u[2] = (w1[0] & 0xffffu) | (w1[1] << 16);
    ah.u[3] = (w1[2] & 0xffffu) | (w1[3] << 16);
    al.u[0] = (w0[0] >> 16) | (w0[1] & 0xffff0000u);
    al.u[1] = (w0[2] >> 16) | (w0[3] & 0xffff0000u);
    al.u[2] = (w1[0] >> 16) | (w1[1] & 0xffff0000u);
    al.u[3] = (w1[2] >> 16) | (w1[3] & 0xffff0000u);
    Ah = ah.h; Al = al.h;
}

// ---------------- prep kernels ----------------

__global__ void k_base(const float* __restrict__ emb,
                       const float* __restrict__ gw0, const float* __restrict__ gb0,
                       const float* __restrict__ fw0, const float* __restrict__ fb0,
                       float* __restrict__ base_g, float* __restrict__ base_f)
{
    int blk = blockIdx.x;            // 256 blocks
    int n     = blk >> 2;
    int half  = (blk >> 1) & 1;
    int which = blk & 1;
    int c = half * 256 + threadIdx.x;
    const float* W    = which ? fw0 : gw0;
    const float* bias = which ? fb0 : gb0;
    float* dst        = which ? base_f : base_g;
    int off           = which ? 64 : 128;
    const float* e = emb + n * 64;
    float acc = bias[c];
    #pragma unroll 8
    for (int k = 0; k < 64; ++k)
        acc = fmaf(e[k], W[(off + k) * 512 + c], acc);
    dst[n * 512 + c] = acc;
}

// w2P[node][a][d] = fw2[a][2*node+d]
__global__ void k_w2p(const float* __restrict__ fw2, float* __restrict__ w2P)
{
    int tid = blockIdx.x * 256 + threadIdx.x;   // grid 256 -> 65536
    int c = tid >> 9, a = tid & 511;            // c = 2*node+d
    int node = c >> 1, d = c & 1;
    w2P[(node * 512 + a) * 2 + d] = fw2[a * 128 + c];
}

// Fragment-linear f16 hi/lo splits (B-operand layout for mfma 16x16x32):
//  fw1/gw1 (512x512): frag[(kstep*32+ntg)*64+l][j] = W[kstep*32+(l>>4)*8+j][ntg*16+(l&15)]
//  fw0 rows 0..63:    frag[(kstep*32+ntg)*64+l][j] (kstep 0..1)
//  gw2 (512x64):      frag[(kstep*4+ntg)*64+l][j]
__global__ void k_splitw(const float* __restrict__ fw0, const float* __restrict__ fw1,
                         const float* __restrict__ gw1, const float* __restrict__ gw2,
                         _Float16* __restrict__ fw0h, _Float16* __restrict__ fw0l,
                         _Float16* __restrict__ fw1h, _Float16* __restrict__ fw1l,
                         _Float16* __restrict__ gw1h, _Float16* __restrict__ gw1l,
                         _Float16* __restrict__ gw2h, _Float16* __restrict__ gw2l)
{
    int tid = blockIdx.x * 256 + threadIdx.x;
    if (blockIdx.x < 128) {                       // fw1
        int l = tid & 63, grp = tid >> 6;
        int kstep = grp >> 5, ntg = grp & 31;
        #pragma unroll
        for (int j = 0; j < 8; ++j) {
            int k = kstep * 32 + (l >> 4) * 8 + j;
            int n = ntg * 16 + (l & 15);
            float v = fw1[k * 512 + n];
            _Float16 h = (_Float16)v;
            fw1h[tid * 8 + j] = h;
            fw1l[tid * 8 + j] = (_Float16)(v - (float)h);
        }
    } else if (blockIdx.x < 144) {                // fw0 rows 0..63
        int t2 = tid - 32768;
        int l = t2 & 63, grp = t2 >> 6;
        int kstep = grp >> 5, ntg = grp & 31;
        #pragma unroll
        for (int j = 0; j < 8; ++j) {
            int k = kstep * 32 + (l >> 4) * 8 + j;
            int n = ntg * 16 + (l & 15);
            float v = fw0[k * 512 + n];
            _Float16 h = (_Float16)v;
            fw0h[t2 * 8 + j] = h;
            fw0l[t2 * 8 + j] = (_Float16)(v - (float)h);
        }
    } else if (blockIdx.x < 272) {                // gw1
        int t4 = tid - 36864;
        int l = t4 & 63, grp = t4 >> 6;
        int kstep = grp >> 5, ntg = grp & 31;
        #pragma unroll
        for (int j = 0; j < 8; ++j) {
            int k = kstep * 32 + (l >> 4) * 8 + j;
            int n = ntg * 16 + (l & 15);
            float v = gw1[k * 512 + n];
            _Float16 h = (_Float16)v;
            gw1h[t4 * 8 + j] = h;
            gw1l[t4 * 8 + j] = (_Float16)(v - (float)h);
        }
    } else {                                      // gw2
        int t3 = tid - 69632;                     // 0..4095
        int l = t3 & 63, grp = t3 >> 6;           // grp 0..63
        int kstep = grp >> 2, ntg = grp & 3;
        #pragma unroll
        for (int j = 0; j < 8; ++j) {
            int k = kstep * 32 + (l >> 4) * 8 + j;
            int n = ntg * 16 + (l & 15);
            float v = gw2[k * 64 + n];
            _Float16 h = (_Float16)v;
            gw2h[t3 * 8 + j] = h;
            gw2l[t3 * 8 + j] = (_Float16)(v - (float)h);
        }
    }
}

// ---------------- k_gmlp: g-MLP on MFMA (unchanged from round 6/7) ----------------

__global__ __launch_bounds__(512, 2) void k_gmlp(
    const float* __restrict__ samples, const float* __restrict__ gw0,
    const float* __restrict__ base_g, const float* __restrict__ gb1,
    const float* __restrict__ gb2,
    const _Float16* __restrict__ gw1h, const _Float16* __restrict__ gw1l,
    const _Float16* __restrict__ gw2h, const _Float16* __restrict__ gw2l,
    float* __restrict__ emb_s)
{
    __shared__ __align__(16) unsigned char smem[81920];
    const int t = threadIdx.x, l = t & 63, wv = t >> 6;
    const int q = l >> 4, lr = l & 15;
    const int b = blockIdx.x;

    f32x4 zero4 = {0.f, 0.f, 0.f, 0.f};
    f32x4 acc[4][4];
    #pragma unroll
    for (int mt = 0; mt < 4; ++mt)
        #pragma unroll
        for (int nt = 0; nt < 4; ++nt) acc[mt][nt] = zero4;

    auto stage = [&](int kk, int bq) {
        #pragma unroll
        for (int it = 0; it < 4; ++it) {
            int n = it * 16 + (t >> 5);
            int c = kk * 32 + (t & 31);
            float s0 = samples[b * 128 + 2 * n];
            float s1 = samples[b * 128 + 2 * n + 1];
            float v = fmaf(s0, gw0[(2 * n) * 512 + c],
                      fmaf(s1, gw0[(2 * n + 1) * 512 + c], base_g[n * 512 + c]));
            v = leaky(v);
            int kl = t & 31;
            int sw = (((kl >> 2) ^ (n & 7)) << 2) | (kl & 3);
            *(uint32_t*)(smem + bq * 8192 + n * 128 + sw * 4) = packsplit(v);
        }
    };

    stage(0, 0);
    for (int kk = 0; kk < 16; ++kk) {
        const int pb = kk & 1;
        __syncthreads();
        if (kk < 15) stage(kk + 1, pb ^ 1);

        half8 Ah[4], Al[4];
        #pragma unroll
        for (int mt = 0; mt < 4; ++mt) {
            int row = mt * 16 + lr, f = row & 7;
            const unsigned char* rb = smem + pb * 8192 + row * 128;
            u32x4 w0 = *(const u32x4*)(rb + (((2 * q) ^ f) << 4));
            u32x4 w1 = *(const u32x4*)(rb + (((2 * q + 1) ^ f) << 4));
            unpackA(w0, w1, Ah[mt], Al[mt]);
        }
        #pragma unroll
        for (int nt = 0; nt < 4; ++nt) {
            int ntg = wv * 4 + nt;
            long boff = (long)((kk * 32 + ntg) * 64 + l) * 8;
            half8 Bh = *(const half8*)(gw1h + boff);
            half8 Bl = *(const half8*)(gw1l + boff);
            #pragma unroll
            for (int mt = 0; mt < 4; ++mt) {
                acc[mt][nt] = MFMA16(Ah[mt], Bh, acc[mt][nt]);
                acc[mt][nt] = MFMA16(Ah[mt], Bl, acc[mt][nt]);
                acc[mt][nt] = MFMA16(Al[mt], Bh, acc[mt][nt]);
            }
        }
    }

    const int mt2 = wv >> 1;
    f32x4 acc2[2] = {zero4, zero4};
    #pragma unroll
    for (int half = 0; half < 2; ++half) {
        __syncthreads();
        if ((wv >> 2) == half) {
            #pragma unroll
            for (int nt = 0; nt < 4; ++nt) {
                int col = wv * 64 + nt * 16 + lr;
                float bb = gb1[col];
                int ksl = (col >> 5) - half * 8;
                int kl = col & 31;
                #pragma unroll
                for (int mt = 0; mt < 4; ++mt)
                    #pragma unroll
                    for (int r = 0; r < 4; ++r) {
                        int row = mt * 16 + q * 4 + r;
                        float v = leaky(acc[mt][nt][r] + bb);
                        int sw = (((kl >> 2) ^ (row & 7)) << 2) | (kl & 3);
                        *(uint32_t*)(smem + 16384 + ksl * 8192 + row * 128 + sw * 4)
                            = packsplit(v);
                    }
            }
        }
        __syncthreads();
        #pragma unroll
        for (int ks = 0; ks < 8; ++ks) {
            int kstep = half * 8 + ks;
            int row = mt2 * 16 + lr, f = row & 7;
            const unsigned char* rb = smem + 16384 + ks * 8192 + row * 128;
            u32x4 w0 = *(const u32x4*)(rb + (((2 * q) ^ f) << 4));
            u32x4 w1 = *(const u32x4*)(rb + (((2 * q + 1) ^ f) << 4));
            half8 Ah2, Al2;
            unpackA(w0, w1, Ah2, Al2);
            #pragma unroll
            for (int nt = 0; nt < 2; ++nt) {
                int ntg = (wv & 1) * 2 + nt;
                long boff = (long)((kstep * 4 + ntg) * 64 + l) * 8;
                half8 Bh = *(const half8*)(gw2h + boff);
                half8 Bl = *(const half8*)(gw2l + boff);
                acc2[nt] = MFMA16(Ah2, Bh, acc2[nt]);
                acc2[nt] = MFMA16(Ah2, Bl, acc2[nt]);
                acc2[nt] = MFMA16(Al2, Bh, acc2[nt]);
            }
        }
    }
    #pragma unroll
    for (int nt = 0; nt < 2; ++nt) {
        int col = ((wv & 1) * 2 + nt) * 16 + lr;
        float bb = gb2[col];
        #pragma unroll
        for (int r = 0; r < 4; ++r) {
            int node = mt2 * 16 + q * 4 + r;
            emb_s[b * 4096 + node * 64 + col] = acc2[nt][r] + bb;
        }
    }
}

// ---------------- k_f2: fully fused f-MLP ----------------
// LDS (80 KB):
//   [0, 32768)     h0 hi-plane: [row 64][512 B] (256 cols/super-chunk, granule swz)
//                  (prologue overlay: s_emb [0,16K), s_wadj [16K,32K))
//                  (epilogue overlay: part [0,8K))
//   [32768, 65536) h0 lo-plane
//   [65536, 81920) A0: aggr packed u32 [m 64][256 B], granule-XOR swizzled
// Granule swizzle for planes: kg' = (kg & 16) | ((kg ^ row) & 15), kg = klocal>>3.

__global__ __launch_bounds__(1024) void k_f2(
    const float* __restrict__ graphs, const float* __restrict__ w,
    const float* __restrict__ emb_s, const float* __restrict__ base_f,
    const float* __restrict__ fb1, const float* __restrict__ w2P,
    const float* __restrict__ fb2,
    const _Float16* __restrict__ fw0h, const _Float16* __restrict__ fw0l,
    const _Float16* __restrict__ fw1h, const _Float16* __restrict__ fw1l,
    float* __restrict__ out)
{
    __shared__ __align__(16) unsigned char smem[81920];
    const int t = threadIdx.x, l = t & 63, wv = t >> 6;   // wv 0..15
    const int q = l >> 4, lr = l & 15;
    const int bid = blockIdx.x;
    const int m_blk = (bid & 7) * 256 + (bid >> 3);       // XCD-contiguous
    const int b = m_blk >> 3, g = m_blk & 7;

    // ---- stage emb_s[b] (16 KB) + wadj = graphs[g]*w (16 KB) ----
    {
        float* se = (float*)smem;
        float* sw = (float*)(smem + 16384);
        int idx = t * 4;
        *(float4*)(se + idx) = *(const float4*)(emb_s + b * 4096 + idx);
        float4 gr = *(const float4*)(graphs + g * 4096 + idx);
        float4 ww = *(const float4*)(w + idx);
        float4 m2;
        m2.x = gr.x * ww.x; m2.y = gr.y * ww.y;
        m2.z = gr.z * ww.z; m2.w = gr.w * ww.w;
        *(float4*)(sw + idx) = m2;
    }
    __syncthreads();

    // ---- aggr[m][k] fp32 -> packed A0 frags ----
    {
        const float* se = (const float*)smem;
        const float* sw = (const float*)(smem + 16384);
        int m = t >> 4, k0 = (t & 15) * 4;
        float acc[4] = {0.f, 0.f, 0.f, 0.f};
        for (int j = 0; j < 64; ++j) {
            float wc = sw[j * 64 + m];
            float4 e = *(const float4*)(se + j * 64 + k0);
            acc[0] = fmaf(wc, e.x, acc[0]); acc[1] = fmaf(wc, e.y, acc[1]);
            acc[2] = fmaf(wc, e.z, acc[2]); acc[3] = fmaf(wc, e.w, acc[3]);
        }
        u32x4 p;
        #pragma unroll
        for (int e = 0; e < 4; ++e) p[e] = packsplit(acc[e]);
        int gran = t & 15;
        *(u32x4*)(smem + 65536 + m * 256 + ((gran ^ (m & 7)) << 4)) = p;
    }
    __syncthreads();

    f32x4 zero4 = {0.f, 0.f, 0.f, 0.f};
    f32x4 acc1[4][2];
    #pragma unroll
    for (int mt = 0; mt < 4; ++mt) { acc1[mt][0] = zero4; acc1[mt][1] = zero4; }

    for (int sc = 0; sc < 2; ++sc) {
        // ---- layer0: this wave's 16 cols (global col = sc*256 + wv*16 + lr) ----
        f32x4 c0[4] = {zero4, zero4, zero4, zero4};
        #pragma unroll
        for (int ks = 0; ks < 2; ++ks) {
            half8 Ah[4], Al[4];
            #pragma unroll
            for (int mt = 0; mt < 4; ++mt) {
                int m = mt * 16 + lr, f = m & 7;
                const unsigned char* rb = smem + 65536 + m * 256;
                int gb2 = ks * 8 + 2 * q;
                u32x4 w0 = *(const u32x4*)(rb + (((gb2)     ^ f) << 4));
                u32x4 w1 = *(const u32x4*)(rb + (((gb2 + 1) ^ f) << 4));
                unpackA(w0, w1, Ah[mt], Al[mt]);
            }
            int ntg = sc * 16 + wv;
            long boff = (long)((ks * 32 + ntg) * 64 + l) * 8;
            half8 Bh = *(const half8*)(fw0h + boff);
            half8 Bl = *(const half8*)(fw0l + boff);
            #pragma unroll
            for (int mt = 0; mt < 4; ++mt) {
                c0[mt] = MFMA16(Ah[mt], Bh, c0[mt]);
                c0[mt] = MFMA16(Ah[mt], Bl, c0[mt]);
                c0[mt] = MFMA16(Al[mt], Bh, c0[mt]);
            }
        }
        __syncthreads();   // all waves done reading h0 of prev super-chunk (and staging at sc=0)

        // ---- epilogue: +base_f, leaky, split -> two-plane h0 ----
        {
            int klocal = wv * 16 + lr;
            int kg = klocal >> 3;
            #pragma unroll
            for (int mt = 0; mt < 4; ++mt) {
                #pragma unroll
                for (int r = 0; r < 4; ++r) {
                    int node = mt * 16 + q * 4 + r;
                    float v = leaky(c0[mt][r] +
                                    base_f[node * 512 + sc * 256 + klocal]);
                    _Float16 hi = (_Float16)v;
                    _Float16 lo = (_Float16)(v - (float)hi);
                    int kgp = (kg & 16) | ((kg ^ node) & 15);
                    int byte = node * 512 + kgp * 16 + (lr & 7) * 2;
                    *(_Float16*)(smem + byte)         = hi;
                    *(_Float16*)(smem + 32768 + byte) = lo;
                }
            }
        }
        __syncthreads();   // h0 super-chunk ready

        // ---- layer1: 8 barrier-free K-steps over this super-chunk ----
        #pragma unroll
        for (int kkl = 0; kkl < 8; ++kkl) {
            const int kk = sc * 8 + kkl;
            half8 Ah[4], Al[4];
            #pragma unroll
            for (int mt = 0; mt < 4; ++mt) {
                int row = mt * 16 + lr;
                int kg = kkl * 4 + q;
                int kgp = (kg & 16) | ((kg ^ row) & 15);
                int ab = row * 512 + kgp * 16;
                Ah[mt] = *(const half8*)(smem + ab);
                Al[mt] = *(const half8*)(smem + 32768 + ab);
            }
            #pragma unroll
            for (int nt = 0; nt < 2; ++nt) {
                int ntg = wv * 2 + nt;
                long boff = (long)((kk * 32 + ntg) * 64 + l) * 8;
                half8 Bh = *(const half8*)(fw1h + boff);
                half8 Bl = *(const half8*)(fw1l + boff);
                __builtin_amdgcn_s_setprio(1);
                #pragma unroll
                for (int mt = 0; mt < 4; ++mt) {
                    acc1[mt][nt] = MFMA16(Ah[mt], Bh, acc1[mt][nt]);
                    acc1[mt][nt] = MFMA16(Ah[mt], Bl, acc1[mt][nt]);
                    acc1[mt][nt] = MFMA16(Al[mt], Bh, acc1[mt][nt]);
                }
                __builtin_amdgcn_s_setprio(0);
            }
        }
    }

    __syncthreads();   // layer1 reads done; safe to overlay part into h0hi
    // ---- h1 bias/leaky + fused layer2 partial dots ----
    float* part = (float*)smem;   // [wv 16][node 64][d 2] = 8 KB
    #pragma unroll
    for (int mt = 0; mt < 4; ++mt) {
        float s0[4] = {0.f, 0.f, 0.f, 0.f}, s1[4] = {0.f, 0.f, 0.f, 0.f};
        #pragma unroll
        for (int nt = 0; nt < 2; ++nt) {
            int col = wv * 32 + nt * 16 + lr;
            float bb = fb1[col];
            #pragma unroll
            for (int r = 0; r < 4; ++r) {
                int node = mt * 16 + q * 4 + r;
                float h1 = leaky(acc1[mt][nt][r] + bb);
                float2 w2 = *(const float2*)(w2P + (((size_t)node * 512 + col) << 1));
                s0[r] = fmaf(h1, w2.x, s0[r]);
                s1[r] = fmaf(h1, w2.y, s1[r]);
            }
        }
        #pragma unroll
        for (int r = 0; r < 4; ++r) {
            s0[r] += __shfl_xor(s0[r], 1, 64); s0[r] += __shfl_xor(s0[r], 2, 64);
            s0[r] += __shfl_xor(s0[r], 4, 64); s0[r] += __shfl_xor(s0[r], 8, 64);
            s1[r] += __shfl_xor(s1[r], 1, 64); s1[r] += __shfl_xor(s1[r], 2, 64);
            s1[r] += __shfl_xor(s1[r], 4, 64); s1[r] += __shfl_xor(s1[r], 8, 64);
            if (lr == 0) {
                int node = mt * 16 + q * 4 + r;
                part[wv * 128 + node * 2 + 0] = s0[r];
                part[wv * 128 + node * 2 + 1] = s1[r];
            }
        }
    }
    __syncthreads();
    if (t < 128) {
        float s = 0.f;
        #pragma unroll
        for (int v16 = 0; v16 < 16; ++v16) s += part[v16 * 128 + t];
        out[m_blk * 128 + t] = s + fb2[t];
    }
}

// ---------------- launch ----------------

extern "C" void kernel_launch(void* const* d_in, const int* in_sizes, int n_in,
                              void* d_out, int out_size, void* d_ws, size_t ws_size,
                              hipStream_t stream)
{
    const float* samples    = (const float*)d_in[0];
    const float* graphs     = (const float*)d_in[1];
    const float* embeddings = (const float*)d_in[3];
    const float* w          = (const float*)d_in[4];
    const float* g_w0 = (const float*)d_in[5];
    const float* g_b0 = (const float*)d_in[6];
    const float* g_w1 = (const float*)d_in[7];
    const float* g_b1 = (const float*)d_in[8];
    const float* g_w2 = (const float*)d_in[9];
    const float* g_b2 = (const float*)d_in[10];
    const float* f_w0 = (const float*)d_in[11];
    const float* f_b0 = (const float*)d_in[12];
    const float* f_w1 = (const float*)d_in[13];
    const float* f_b1 = (const float*)d_in[14];
    const float* f_w2 = (const float*)d_in[15];
    const float* f_b2 = (const float*)d_in[16];
    float* out = (float*)d_out;

    float* ws     = (float*)d_ws;
    float* base_g = ws;                    // 32768 f
    float* base_f = ws + 32768;            // 32768 f
    float* w2P    = ws + 65536;            // 65536 f
    float* emb_s  = ws + 131072;           // 1048576 f
    _Float16* f16b = (_Float16*)(ws + 1179648);
    _Float16* fw1h = f16b;                 // 262144 h
    _Float16* fw1l = f16b + 262144;
    _Float16* fw0h = f16b + 524288;        // 32768 h
    _Float16* fw0l = f16b + 557056;
    _Float16* gw1h = f16b + 589824;        // 262144 h
    _Float16* gw1l = f16b + 851968;
    _Float16* gw2h = f16b + 1114112;       // 32768 h
    _Float16* gw2l = f16b + 1146880;       // end ~7.1 MB of ws

    hipLaunchKernelGGL(k_base, dim3(256), dim3(256), 0, stream,
                       embeddings, g_w0, g_b0, f_w0, f_b0, base_g, base_f);
    hipLaunchKernelGGL(k_w2p, dim3(256), dim3(256), 0, stream, f_w2, w2P);
    hipLaunchKernelGGL(k_splitw, dim3(288), dim3(256), 0, stream,
                       f_w0, f_w1, g_w1, g_w2,
                       fw0h, fw0l, fw1h, fw1l, gw1h, gw1l, gw2h, gw2l);
    hipLaunchKernelGGL(k_gmlp, dim3(256), dim3(512), 0, stream,
                       samples, g_w0, base_g, g_b1, g_b2,
                       gw1h, gw1l, gw2h, gw2l, emb_s);
    hipLaunchKernelGGL(k_f2, dim3(2048), dim3(1024), 0, stream,
                       graphs, w, emb_s, base_f, f_b1, w2P, f_b2,
                       fw0h, fw0l, fw1h, fw1l, out);
}